// Round 2
// baseline (1342.859 us; speedup 1.0000x reference)
//
#include <hip/hip_runtime.h>
#include <hip/hip_bf16.h>

// B=4, S=2048, H=1024. Inputs/outputs fp32. MFMA in split-bf16 (hi/lo) for
// Q/K path (3-pass), plain bf16 for V/PV. Softmax fp32.
// ws layout (ushort elems):
//   Xh[8.39M] Xl[8.39M] Wqh Wql Wkh Wkl Wvh Wvl [1.05M each]
//   Qh Ql Kh Kl [8.39M each] Vt[8.39M]          total ~124 MiB

typedef __attribute__((ext_vector_type(4))) float f32x4;
typedef __attribute__((ext_vector_type(8))) short bf16x8;
typedef __attribute__((ext_vector_type(4))) unsigned short us4;

#define MFMA16(a, b, c) __builtin_amdgcn_mfma_f32_16x16x32_bf16((a), (b), (c), 0, 0, 0)

static __device__ __forceinline__ unsigned short f2bf_u(float x) {
  __hip_bfloat16 h = __float2bfloat16(x);
  return *reinterpret_cast<unsigned short*>(&h);
}
static __device__ __forceinline__ float bfu2f(unsigned short u) {
  __hip_bfloat16 h;
  *reinterpret_cast<unsigned short*>(&h) = u;
  return __bfloat162float(h);
}

// fp32 -> (hi, lo) bf16 planes. n4 = n/4.
__global__ __launch_bounds__(256) void split_kernel(
    const float* __restrict__ in, unsigned short* __restrict__ hi,
    unsigned short* __restrict__ lo, int n4) {
  int i = blockIdx.x * 256 + threadIdx.x;
  const int stride = gridDim.x * 256;
  for (; i < n4; i += stride) {
    f32x4 v = reinterpret_cast<const f32x4*>(in)[i];
    us4 h, l;
#pragma unroll
    for (int j = 0; j < 4; j++) {
      unsigned short hu = f2bf_u(v[j]);
      h[j] = hu;
      l[j] = f2bf_u(v[j] - bfu2f(hu));
    }
    reinterpret_cast<us4*>(hi)[i] = h;
    reinterpret_cast<us4*>(lo)[i] = l;
  }
}

// O[m][n] = sum_k X[m][k]*W[n][k] + bias[n], split-bf16 3-pass.
// Output written as hi/lo bf16 planes. 64x64 tile, 4 waves (2x2).
__global__ __launch_bounds__(256) void proj_qk_kernel(
    const unsigned short* __restrict__ Xh, const unsigned short* __restrict__ Xl,
    const unsigned short* __restrict__ Wh, const unsigned short* __restrict__ Wl,
    const float* __restrict__ bias,
    unsigned short* __restrict__ Oh, unsigned short* __restrict__ Ol) {
  const int tid = threadIdx.x;
  const int lane = tid & 63;
  const int wid = tid >> 6;
  const int wr = wid >> 1;
  const int wc = wid & 1;
  const int lrow = lane & 15;
  const int kg = lane >> 4;
  const int bm = blockIdx.x * 64;
  const int bn = blockIdx.y * 64;

  const size_t a0 = (size_t)(bm + wr * 32 + lrow) * 1024 + kg * 8;
  const size_t a1 = a0 + (size_t)16 * 1024;
  const size_t b0 = (size_t)(bn + wc * 32 + lrow) * 1024 + kg * 8;
  const size_t b1 = b0 + (size_t)16 * 1024;

  f32x4 acc00 = {}, acc01 = {}, acc10 = {}, acc11 = {};
  for (int k = 0; k < 1024; k += 32) {
    bf16x8 a0h = *(const bf16x8*)(Xh + a0 + k);
    bf16x8 a0l = *(const bf16x8*)(Xl + a0 + k);
    bf16x8 a1h = *(const bf16x8*)(Xh + a1 + k);
    bf16x8 a1l = *(const bf16x8*)(Xl + a1 + k);
    bf16x8 b0h = *(const bf16x8*)(Wh + b0 + k);
    bf16x8 b0l = *(const bf16x8*)(Wl + b0 + k);
    bf16x8 b1h = *(const bf16x8*)(Wh + b1 + k);
    bf16x8 b1l = *(const bf16x8*)(Wl + b1 + k);
    acc00 = MFMA16(a0h, b0h, acc00);
    acc00 = MFMA16(a0h, b0l, acc00);
    acc00 = MFMA16(a0l, b0h, acc00);
    acc01 = MFMA16(a0h, b1h, acc01);
    acc01 = MFMA16(a0h, b1l, acc01);
    acc01 = MFMA16(a0l, b1h, acc01);
    acc10 = MFMA16(a1h, b0h, acc10);
    acc10 = MFMA16(a1h, b0l, acc10);
    acc10 = MFMA16(a1l, b0h, acc10);
    acc11 = MFMA16(a1h, b1h, acc11);
    acc11 = MFMA16(a1h, b1l, acc11);
    acc11 = MFMA16(a1l, b1h, acc11);
  }

  // C layout: col = lane&15, row = (lane>>4)*4 + i
  const int m00 = bm + wr * 32 + kg * 4;
  const int n00 = bn + wc * 32 + lrow;
#define STORE_FRAG(AR, BC, ACC)                                              \
  {                                                                          \
    const int n = n00 + (BC)*16;                                             \
    const float bv = bias[n];                                                \
    const int m0 = m00 + (AR)*16;                                            \
    for (int i = 0; i < 4; i++) {                                            \
      float val = (ACC)[i] + bv;                                             \
      unsigned short hu = f2bf_u(val);                                       \
      Oh[(size_t)(m0 + i) * 1024 + n] = hu;                                  \
      Ol[(size_t)(m0 + i) * 1024 + n] = f2bf_u(val - bfu2f(hu));             \
    }                                                                        \
  }
  STORE_FRAG(0, 0, acc00)
  STORE_FRAG(0, 1, acc01)
  STORE_FRAG(1, 0, acc10)
  STORE_FRAG(1, 1, acc11)
#undef STORE_FRAG
}

// V projection, 1-pass bf16, output transposed: Vt[batch][d][key] bf16.
__global__ __launch_bounds__(256) void proj_v_kernel(
    const unsigned short* __restrict__ Xh, const unsigned short* __restrict__ Wh,
    const float* __restrict__ bias, unsigned short* __restrict__ Vt) {
  const int tid = threadIdx.x;
  const int lane = tid & 63;
  const int wid = tid >> 6;
  const int wr = wid >> 1;
  const int wc = wid & 1;
  const int lrow = lane & 15;
  const int kg = lane >> 4;
  const int bm = blockIdx.x * 64;
  const int bn = blockIdx.y * 64;

  const size_t a0 = (size_t)(bm + wr * 32 + lrow) * 1024 + kg * 8;
  const size_t a1 = a0 + (size_t)16 * 1024;
  const size_t b0 = (size_t)(bn + wc * 32 + lrow) * 1024 + kg * 8;
  const size_t b1 = b0 + (size_t)16 * 1024;

  f32x4 acc00 = {}, acc01 = {}, acc10 = {}, acc11 = {};
  for (int k = 0; k < 1024; k += 32) {
    bf16x8 a0h = *(const bf16x8*)(Xh + a0 + k);
    bf16x8 a1h = *(const bf16x8*)(Xh + a1 + k);
    bf16x8 b0h = *(const bf16x8*)(Wh + b0 + k);
    bf16x8 b1h = *(const bf16x8*)(Wh + b1 + k);
    acc00 = MFMA16(a0h, b0h, acc00);
    acc01 = MFMA16(a0h, b1h, acc01);
    acc10 = MFMA16(a1h, b0h, acc10);
    acc11 = MFMA16(a1h, b1h, acc11);
  }

  const int m00 = bm + wr * 32 + kg * 4;
  const int n00 = bn + wc * 32 + lrow;
#define STORE_FRAG(AR, BC, ACC)                                              \
  {                                                                          \
    const int n = n00 + (BC)*16;                                             \
    const float bv = bias[n];                                                \
    const int m0 = m00 + (AR)*16;                                            \
    const int batch = m0 >> 11;                                              \
    const int ml = m0 & 2047;                                                \
    us4 pk;                                                                  \
    for (int i = 0; i < 4; i++) pk[i] = f2bf_u((ACC)[i] + bv);               \
    *reinterpret_cast<us4*>(&Vt[((size_t)batch * 1024 + n) * 2048 + ml]) = pk; \
  }
  STORE_FRAG(0, 0, acc00)
  STORE_FRAG(0, 1, acc01)
  STORE_FRAG(1, 0, acc10)
  STORE_FRAG(1, 1, acc11)
#undef STORE_FRAG
}

// One block per (batch, 16 q-rows). 8 waves / 512 threads.
__global__ __launch_bounds__(512) void attn_kernel(
    const unsigned short* __restrict__ Qh, const unsigned short* __restrict__ Ql,
    const unsigned short* __restrict__ Kh, const unsigned short* __restrict__ Kl,
    const unsigned short* __restrict__ Vt, float* __restrict__ out) {
  __shared__ float S[16][2056];  // +8 pad to break 8KB-stride bank conflicts
  __shared__ float red[16][32];
  __shared__ float rowmax[16];
  __shared__ float rowinv[16];

  const int tid = threadIdx.x;
  const int lane = tid & 63;
  const int wid = tid >> 6;  // 0..7
  const int lrow = lane & 15;
  const int kg = lane >> 4;  // 0..3
  const int b = blockIdx.y;
  const int q0 = blockIdx.x * 16;
  const size_t qoff = ((size_t)b * 2048 + q0) * 1024 + (size_t)lrow * 1024 + kg * 8;
  const size_t koff = (size_t)b * 2048 * 1024;

  // ---- Phase 1: scores = Q K^T (split-bf16, 3-pass) ----
  for (int cf = 0; cf < 16; cf += 2) {
    const int c0 = wid * 256 + cf * 16;
    const size_t k0 = koff + (size_t)(c0 + lrow) * 1024 + kg * 8;
    const size_t k1 = k0 + (size_t)16 * 1024;
    f32x4 s0 = {}, s1 = {};
    for (int k = 0; k < 1024; k += 32) {
      bf16x8 qh = *(const bf16x8*)(Qh + qoff + k);
      bf16x8 ql = *(const bf16x8*)(Ql + qoff + k);
      bf16x8 kh0 = *(const bf16x8*)(Kh + k0 + k);
      bf16x8 kl0 = *(const bf16x8*)(Kl + k0 + k);
      bf16x8 kh1 = *(const bf16x8*)(Kh + k1 + k);
      bf16x8 kl1 = *(const bf16x8*)(Kl + k1 + k);
      s0 = MFMA16(qh, kh0, s0);
      s0 = MFMA16(qh, kl0, s0);
      s0 = MFMA16(ql, kh0, s0);
      s1 = MFMA16(qh, kh1, s1);
      s1 = MFMA16(qh, kl1, s1);
      s1 = MFMA16(ql, kh1, s1);
    }
#pragma unroll
    for (int i = 0; i < 4; i++) {
      S[kg * 4 + i][c0 + lrow] = s0[i];
      S[kg * 4 + i][c0 + 16 + lrow] = s1[i];
    }
  }
  __syncthreads();

  // ---- Phase 2: softmax (fp32, exact max, deferred normalization) ----
  const int r = tid & 15;
  const int g = tid >> 4;  // 0..31
  {
    float pm = -3.0e38f;
    for (int c = g; c < 2048; c += 32) pm = fmaxf(pm, S[r][c]);
    red[r][g] = pm;
  }
  __syncthreads();
  if (tid < 16) {
    float m = red[tid][0];
    for (int j = 1; j < 32; j++) m = fmaxf(m, red[tid][j]);
    rowmax[tid] = m;
  }
  __syncthreads();
  {
    const float m = rowmax[r];
    float ps = 0.f;
    for (int c = g; c < 2048; c += 32) {
      float e = __expf(S[r][c] - m);
      S[r][c] = e;
      ps += e;
    }
    red[r][g] = ps;
  }
  __syncthreads();
  if (tid < 16) {
    float s = 0.f;
    for (int j = 0; j < 32; j++) s += red[tid][j];
    rowinv[tid] = 1.0f / s;
  }
  __syncthreads();

  // ---- Phase 3: out = (P @ V) * inv_rowsum ----
  {
    const size_t vb = (size_t)b * 1024 * 2048;
    f32x4 acc[8];
#pragma unroll
    for (int i = 0; i < 8; i++) acc[i] = f32x4{0.f, 0.f, 0.f, 0.f};
    const int dbase = wid * 128 + lrow;
    for (int kk = 0; kk < 2048; kk += 32) {
      const float* sp = &S[lrow][kk + kg * 8];
      bf16x8 pa;
#pragma unroll
      for (int j = 0; j < 8; j++) pa[j] = (short)f2bf_u(sp[j]);
#pragma unroll
      for (int cf = 0; cf < 8; cf++) {
        const unsigned short* vp = Vt + vb + (size_t)(dbase + cf * 16) * 2048 + kk + kg * 8;
        acc[cf] = MFMA16(pa, *(const bf16x8*)vp, acc[cf]);
      }
    }
    float inv[4];
#pragma unroll
    for (int i = 0; i < 4; i++) inv[i] = rowinv[kg * 4 + i];
#pragma unroll
    for (int cf = 0; cf < 8; cf++) {
      const int d = dbase + cf * 16;
#pragma unroll
      for (int i = 0; i < 4; i++) {
        const int row = kg * 4 + i;
        out[((size_t)b * 2048 + q0 + row) * 1024 + d] = acc[cf][i] * inv[i];
      }
    }
  }
}

extern "C" void kernel_launch(void* const* d_in, const int* in_sizes, int n_in,
                              void* d_out, int out_size, void* d_ws, size_t ws_size,
                              hipStream_t stream) {
  const float* x  = (const float*)d_in[0];
  const float* Wq = (const float*)d_in[1];
  const float* bq = (const float*)d_in[2];
  const float* Wk = (const float*)d_in[3];
  const float* bk = (const float*)d_in[4];
  const float* Wv = (const float*)d_in[5];
  const float* bv = (const float*)d_in[6];
  float* o = (float*)d_out;

  const size_t NX = (size_t)8192 * 1024;  // 8,388,608
  const size_t NW = (size_t)1024 * 1024;  // 1,048,576
  unsigned short* p = (unsigned short*)d_ws;
  unsigned short* Xh = p; p += NX;
  unsigned short* Xl = p; p += NX;
  unsigned short* Wqh = p; p += NW;
  unsigned short* Wql = p; p += NW;
  unsigned short* Wkh = p; p += NW;
  unsigned short* Wkl = p; p += NW;
  unsigned short* Wvh = p; p += NW;
  unsigned short* Wvl = p; p += NW;
  unsigned short* Qh = p; p += NX;
  unsigned short* Ql = p; p += NX;
  unsigned short* Kh = p; p += NX;
  unsigned short* Kl = p; p += NX;
  unsigned short* Vt = p; p += NX;

  split_kernel<<<2048, 256, 0, stream>>>(x, Xh, Xl, (int)(NX / 4));
  split_kernel<<<1024, 256, 0, stream>>>(Wq, Wqh, Wql, (int)(NW / 4));
  split_kernel<<<1024, 256, 0, stream>>>(Wk, Wkh, Wkl, (int)(NW / 4));
  split_kernel<<<1024, 256, 0, stream>>>(Wv, Wvh, Wvl, (int)(NW / 4));

  dim3 g1(128, 16), b1(256);
  proj_qk_kernel<<<g1, b1, 0, stream>>>(Xh, Xl, Wqh, Wql, bq, Qh, Ql);
  proj_qk_kernel<<<g1, b1, 0, stream>>>(Xh, Xl, Wkh, Wkl, bk, Kh, Kl);
  proj_v_kernel<<<g1, b1, 0, stream>>>(Xh, Wvh, bv, Vt);

  dim3 g2(128, 4), b2(512);
  attn_kernel<<<g2, b2, 0, stream>>>(Qh, Ql, Kh, Kl, Vt, o);
}

// Round 3
// 998.582 us; speedup vs baseline: 1.3448x; 1.3448x over previous
//
#include <hip/hip_runtime.h>
#include <hip/hip_bf16.h>

// B=4, S=2048, H=1024. Inputs/outputs fp32. MFMA in split-bf16 (hi/lo) for
// Q/K path (3-pass), plain bf16 for V/PV. Softmax fp32, exact.
// ws layout (ushort elems):
//   Xh[8.39M] Xl[8.39M] Wqh Wql Wkh Wkl Wvh Wvl [1.05M each]
//   Qh Ql Kh Kl [8.39M each] Vt[8.39M]          total ~124 MiB

typedef __attribute__((ext_vector_type(4))) float f32x4;
typedef __attribute__((ext_vector_type(16))) float f32x16;
typedef __attribute__((ext_vector_type(8))) short bf16x8;
typedef __attribute__((ext_vector_type(4))) unsigned short us4;

#define MFMA16(a, b, c) __builtin_amdgcn_mfma_f32_16x16x32_bf16((a), (b), (c), 0, 0, 0)
#define MFMA32(a, b, c) __builtin_amdgcn_mfma_f32_32x32x16_bf16((a), (b), (c), 0, 0, 0)

static __device__ __forceinline__ unsigned short f2bf_u(float x) {
  __hip_bfloat16 h = __float2bfloat16(x);
  return *reinterpret_cast<unsigned short*>(&h);
}
static __device__ __forceinline__ float bfu2f(unsigned short u) {
  __hip_bfloat16 h;
  *reinterpret_cast<unsigned short*>(&h) = u;
  return __bfloat162float(h);
}

// fp32 -> (hi, lo) bf16 planes. n4 = n/4.
__global__ __launch_bounds__(256) void split_kernel(
    const float* __restrict__ in, unsigned short* __restrict__ hi,
    unsigned short* __restrict__ lo, int n4) {
  int i = blockIdx.x * 256 + threadIdx.x;
  const int stride = gridDim.x * 256;
  for (; i < n4; i += stride) {
    f32x4 v = reinterpret_cast<const f32x4*>(in)[i];
    us4 h, l;
#pragma unroll
    for (int j = 0; j < 4; j++) {
      unsigned short hu = f2bf_u(v[j]);
      h[j] = hu;
      l[j] = f2bf_u(v[j] - bfu2f(hu));
    }
    reinterpret_cast<us4*>(hi)[i] = h;
    reinterpret_cast<us4*>(lo)[i] = l;
  }
}

// O[m][n] = sum_k X[m][k]*W[n][k] + bias[n], split-bf16 3-pass.
// Output written as hi/lo bf16 planes. 64x64 tile, 4 waves (2x2).
__global__ __launch_bounds__(256) void proj_qk_kernel(
    const unsigned short* __restrict__ Xh, const unsigned short* __restrict__ Xl,
    const unsigned short* __restrict__ Wh, const unsigned short* __restrict__ Wl,
    const float* __restrict__ bias,
    unsigned short* __restrict__ Oh, unsigned short* __restrict__ Ol) {
  const int tid = threadIdx.x;
  const int lane = tid & 63;
  const int wid = tid >> 6;
  const int wr = wid >> 1;
  const int wc = wid & 1;
  const int lrow = lane & 15;
  const int kg = lane >> 4;
  const int bm = blockIdx.x * 64;
  const int bn = blockIdx.y * 64;

  const size_t a0 = (size_t)(bm + wr * 32 + lrow) * 1024 + kg * 8;
  const size_t a1 = a0 + (size_t)16 * 1024;
  const size_t b0 = (size_t)(bn + wc * 32 + lrow) * 1024 + kg * 8;
  const size_t b1 = b0 + (size_t)16 * 1024;

  f32x4 acc00 = {}, acc01 = {}, acc10 = {}, acc11 = {};
  for (int k = 0; k < 1024; k += 32) {
    bf16x8 a0h = *(const bf16x8*)(Xh + a0 + k);
    bf16x8 a0l = *(const bf16x8*)(Xl + a0 + k);
    bf16x8 a1h = *(const bf16x8*)(Xh + a1 + k);
    bf16x8 a1l = *(const bf16x8*)(Xl + a1 + k);
    bf16x8 b0h = *(const bf16x8*)(Wh + b0 + k);
    bf16x8 b0l = *(const bf16x8*)(Wl + b0 + k);
    bf16x8 b1h = *(const bf16x8*)(Wh + b1 + k);
    bf16x8 b1l = *(const bf16x8*)(Wl + b1 + k);
    acc00 = MFMA16(a0h, b0h, acc00);
    acc00 = MFMA16(a0h, b0l, acc00);
    acc00 = MFMA16(a0l, b0h, acc00);
    acc01 = MFMA16(a0h, b1h, acc01);
    acc01 = MFMA16(a0h, b1l, acc01);
    acc01 = MFMA16(a0l, b1h, acc01);
    acc10 = MFMA16(a1h, b0h, acc10);
    acc10 = MFMA16(a1h, b0l, acc10);
    acc10 = MFMA16(a1l, b0h, acc10);
    acc11 = MFMA16(a1h, b1h, acc11);
    acc11 = MFMA16(a1h, b1l, acc11);
    acc11 = MFMA16(a1l, b1h, acc11);
  }

  // C layout: col = lane&15, row = (lane>>4)*4 + i
  const int m00 = bm + wr * 32 + kg * 4;
  const int n00 = bn + wc * 32 + lrow;
#define STORE_FRAG(AR, BC, ACC)                                              \
  {                                                                          \
    const int n = n00 + (BC)*16;                                             \
    const float bv = bias[n];                                                \
    const int m0 = m00 + (AR)*16;                                            \
    for (int i = 0; i < 4; i++) {                                            \
      float val = (ACC)[i] + bv;                                             \
      unsigned short hu = f2bf_u(val);                                       \
      Oh[(size_t)(m0 + i) * 1024 + n] = hu;                                  \
      Ol[(size_t)(m0 + i) * 1024 + n] = f2bf_u(val - bfu2f(hu));             \
    }                                                                        \
  }
  STORE_FRAG(0, 0, acc00)
  STORE_FRAG(0, 1, acc01)
  STORE_FRAG(1, 0, acc10)
  STORE_FRAG(1, 1, acc11)
#undef STORE_FRAG
}

// V projection, 1-pass bf16, output transposed: Vt[batch][d][key] bf16.
__global__ __launch_bounds__(256) void proj_v_kernel(
    const unsigned short* __restrict__ Xh, const unsigned short* __restrict__ Wh,
    const float* __restrict__ bias, unsigned short* __restrict__ Vt) {
  const int tid = threadIdx.x;
  const int lane = tid & 63;
  const int wid = tid >> 6;
  const int wr = wid >> 1;
  const int wc = wid & 1;
  const int lrow = lane & 15;
  const int kg = lane >> 4;
  const int bm = blockIdx.x * 64;
  const int bn = blockIdx.y * 64;

  const size_t a0 = (size_t)(bm + wr * 32 + lrow) * 1024 + kg * 8;
  const size_t a1 = a0 + (size_t)16 * 1024;
  const size_t b0 = (size_t)(bn + wc * 32 + lrow) * 1024 + kg * 8;
  const size_t b1 = b0 + (size_t)16 * 1024;

  f32x4 acc00 = {}, acc01 = {}, acc10 = {}, acc11 = {};
  for (int k = 0; k < 1024; k += 32) {
    bf16x8 a0h = *(const bf16x8*)(Xh + a0 + k);
    bf16x8 a1h = *(const bf16x8*)(Xh + a1 + k);
    bf16x8 b0h = *(const bf16x8*)(Wh + b0 + k);
    bf16x8 b1h = *(const bf16x8*)(Wh + b1 + k);
    acc00 = MFMA16(a0h, b0h, acc00);
    acc01 = MFMA16(a0h, b1h, acc01);
    acc10 = MFMA16(a1h, b0h, acc10);
    acc11 = MFMA16(a1h, b1h, acc11);
  }

  const int m00 = bm + wr * 32 + kg * 4;
  const int n00 = bn + wc * 32 + lrow;
#define STORE_FRAG(AR, BC, ACC)                                              \
  {                                                                          \
    const int n = n00 + (BC)*16;                                             \
    const float bv = bias[n];                                                \
    const int m0 = m00 + (AR)*16;                                            \
    const int batch = m0 >> 11;                                              \
    const int ml = m0 & 2047;                                                \
    us4 pk;                                                                  \
    for (int i = 0; i < 4; i++) pk[i] = f2bf_u((ACC)[i] + bv);               \
    *reinterpret_cast<us4*>(&Vt[((size_t)batch * 1024 + n) * 2048 + ml]) = pk; \
  }
  STORE_FRAG(0, 0, acc00)
  STORE_FRAG(0, 1, acc01)
  STORE_FRAG(1, 0, acc10)
  STORE_FRAG(1, 1, acc11)
#undef STORE_FRAG
}

// attn v3: one block per (batch, 32 q-rows). 8 waves / 512 threads.
// Swapped QK^T (A = K-rows, B = Q-cols) in 32x32x16 MFMA; S entirely in
// registers (8 x f32x16 per lane, lane holds q = lane&31, 128 k-values).
// Exact softmax: in-register reduce + cross-wave LDS. P -> bf16 in
// XOR-swizzled LDS [32][2048]. PV in 32x32x16 from LDS-P + global Vt.
__global__ __launch_bounds__(512, 2) void attn_kernel(
    const unsigned short* __restrict__ Qh, const unsigned short* __restrict__ Ql,
    const unsigned short* __restrict__ Kh, const unsigned short* __restrict__ Kl,
    const unsigned short* __restrict__ Vt, float* __restrict__ out) {
  __shared__ unsigned short P[32 * 2048];  // 128 KB
  __shared__ float redM[8][32];
  __shared__ float redS[8][32];
  __shared__ float rowinv[32];

  const int tid = threadIdx.x;
  const int lane = tid & 63;
  const int wid = tid >> 6;   // 0..7: owns k-cols [wid*256, +256) and d-cols [wid*128, +128)
  const int lq = lane & 31;   // q index (B-col) / matrix row (A)
  const int hi = lane >> 5;
  const int lk8 = hi * 8;     // k-subgroup offset within 16
  const int b = blockIdx.y;
  const int q0 = blockIdx.x * 32;

  // ---- Phase 1: S^T chunk [256 k][32 q] in registers ----
  f32x16 acc[8];
#pragma unroll
  for (int g = 0; g < 8; g++)
#pragma unroll
    for (int r = 0; r < 16; r++) acc[g][r] = 0.f;

  const size_t qrow = ((size_t)b * 2048 + q0 + lq) * 1024 + lk8;
  const size_t krow = ((size_t)b * 2048 + wid * 256 + lq) * 1024 + lk8;

  for (int kk = 0; kk < 1024; kk += 16) {
    bf16x8 qh = *(const bf16x8*)(Qh + qrow + kk);
    bf16x8 ql = *(const bf16x8*)(Ql + qrow + kk);
#pragma unroll
    for (int g = 0; g < 8; g++) {
      const size_t ko = krow + (size_t)g * 32 * 1024 + kk;
      bf16x8 kh = *(const bf16x8*)(Kh + ko);
      bf16x8 kl = *(const bf16x8*)(Kl + ko);
      acc[g] = MFMA32(kh, qh, acc[g]);
      acc[g] = MFMA32(kl, qh, acc[g]);
      acc[g] = MFMA32(kh, ql, acc[g]);
    }
  }

  // ---- Phase 2: softmax (exact row max, fp32 sum) ----
  float m = -3.0e38f;
#pragma unroll
  for (int g = 0; g < 8; g++)
#pragma unroll
    for (int r = 0; r < 16; r++) m = fmaxf(m, acc[g][r]);
  m = fmaxf(m, __shfl_xor(m, 32));
  if (hi == 0) redM[wid][lq] = m;
  __syncthreads();
  float M = redM[0][lq];
#pragma unroll
  for (int w = 1; w < 8; w++) M = fmaxf(M, redM[w][lq]);

  float s = 0.f;
#pragma unroll
  for (int g = 0; g < 8; g++)
#pragma unroll
    for (int r = 0; r < 16; r++) {
      float e = __expf(acc[g][r] - M);
      acc[g][r] = e;
      s += e;
    }
  s += __shfl_xor(s, 32);
  if (hi == 0) redS[wid][lq] = s;
  __syncthreads();
  if (tid < 32) {
    float ss = 0.f;
#pragma unroll
    for (int w = 0; w < 8; w++) ss += redS[w][tid];
    rowinv[tid] = 1.0f / ss;
  }

  // ---- P -> bf16 LDS, XOR-swizzled (byte ^= (row&7)<<4) ----
  // C layout 32x32: k-row within block = (r&3) + 8*(r>>2) + 4*hi
  const int swz = (lq & 7) << 3;  // in ushort-index units
  const int pbase = lq * 2048 + wid * 256 + 4 * hi;
#pragma unroll
  for (int g = 0; g < 8; g++) {
#pragma unroll
    for (int qd = 0; qd < 4; qd++) {
      us4 pk;
#pragma unroll
      for (int i = 0; i < 4; i++) pk[i] = f2bf_u(acc[g][qd * 4 + i]);
      *(us4*)&P[(pbase + g * 32 + qd * 8) ^ swz] = pk;
    }
  }
  __syncthreads();

  // ---- Phase 3: O = P @ V, 32x32x16 (A = LDS P, B = global Vt) ----
  f32x16 o[4];
#pragma unroll
  for (int df = 0; df < 4; df++)
#pragma unroll
    for (int r = 0; r < 16; r++) o[df][r] = 0.f;

  const size_t vrow = ((size_t)b * 1024 + wid * 128 + lq) * 2048 + lk8;
  const int prow = lq * 2048 + lk8;
  for (int kk = 0; kk < 2048; kk += 16) {
    bf16x8 pa = *(const bf16x8*)&P[(prow + kk) ^ swz];
#pragma unroll
    for (int df = 0; df < 4; df++) {
      bf16x8 vv = *(const bf16x8*)(Vt + vrow + (size_t)df * 32 * 2048 + kk);
      o[df] = MFMA32(pa, vv, o[df]);
    }
  }

  // ---- Epilogue: scale by 1/rowsum, store fp32 ----
  float rv[16];
#pragma unroll
  for (int r = 0; r < 16; r++) rv[r] = rowinv[(r & 3) + 8 * (r >> 2) + 4 * hi];
#pragma unroll
  for (int df = 0; df < 4; df++) {
    const int d = wid * 128 + df * 32 + lq;
#pragma unroll
    for (int r = 0; r < 16; r++) {
      const int q = (r & 3) + 8 * (r >> 2) + 4 * hi;
      out[((size_t)b * 2048 + q0 + q) * 1024 + d] = o[df][r] * rv[r];
    }
  }
}

extern "C" void kernel_launch(void* const* d_in, const int* in_sizes, int n_in,
                              void* d_out, int out_size, void* d_ws, size_t ws_size,
                              hipStream_t stream) {
  const float* x  = (const float*)d_in[0];
  const float* Wq = (const float*)d_in[1];
  const float* bq = (const float*)d_in[2];
  const float* Wk = (const float*)d_in[3];
  const float* bk = (const float*)d_in[4];
  const float* Wv = (const float*)d_in[5];
  const float* bv = (const float*)d_in[6];
  float* o = (float*)d_out;

  const size_t NX = (size_t)8192 * 1024;  // 8,388,608
  const size_t NW = (size_t)1024 * 1024;  // 1,048,576
  unsigned short* p = (unsigned short*)d_ws;
  unsigned short* Xh = p; p += NX;
  unsigned short* Xl = p; p += NX;
  unsigned short* Wqh = p; p += NW;
  unsigned short* Wql = p; p += NW;
  unsigned short* Wkh = p; p += NW;
  unsigned short* Wkl = p; p += NW;
  unsigned short* Wvh = p; p += NW;
  unsigned short* Wvl = p; p += NW;
  unsigned short* Qh = p; p += NX;
  unsigned short* Ql = p; p += NX;
  unsigned short* Kh = p; p += NX;
  unsigned short* Kl = p; p += NX;
  unsigned short* Vt = p; p += NX;

  split_kernel<<<2048, 256, 0, stream>>>(x, Xh, Xl, (int)(NX / 4));
  split_kernel<<<1024, 256, 0, stream>>>(Wq, Wqh, Wql, (int)(NW / 4));
  split_kernel<<<1024, 256, 0, stream>>>(Wk, Wkh, Wkl, (int)(NW / 4));
  split_kernel<<<1024, 256, 0, stream>>>(Wv, Wvh, Wvl, (int)(NW / 4));

  dim3 g1(128, 16), b1(256);
  proj_qk_kernel<<<g1, b1, 0, stream>>>(Xh, Xl, Wqh, Wql, bq, Qh, Ql);
  proj_qk_kernel<<<g1, b1, 0, stream>>>(Xh, Xl, Wkh, Wkl, bk, Kh, Kl);
  proj_v_kernel<<<g1, b1, 0, stream>>>(Xh, Wvh, bv, Vt);

  dim3 g2(64, 4), b2(512);
  attn_kernel<<<g2, b2, 0, stream>>>(Qh, Ql, Kh, Kl, Vt, o);
}

// Round 4
// 828.344 us; speedup vs baseline: 1.6211x; 1.2055x over previous
//
#include <hip/hip_runtime.h>
#include <hip/hip_bf16.h>

// B=4, S=2048, H=1024. Inputs/outputs fp32.
// Q/K: split-bf16 hi/lo 3-pass. V/PV: 1-pass bf16. Softmax fp32 exact.
// Attn operands stored in MFMA-native tiles:
//   Q,K planes: [b][s/32][h/16][srow 32][h 16]  (ushort)
//   Vt:         [b][d/32][k/16][drow 32][k 16]  (ushort)
// ws: Qh Ql Kh Kl Vt [8.39M ushort each] + Wqh Wql Wkh Wkl Wvh [1.05M each]

typedef __attribute__((ext_vector_type(4))) float f32x4;
typedef __attribute__((ext_vector_type(16))) float f32x16;
typedef __attribute__((ext_vector_type(8))) short bf16x8;
typedef __attribute__((ext_vector_type(4))) unsigned short us4;

#define MFMA16(a, b, c) __builtin_amdgcn_mfma_f32_16x16x32_bf16((a), (b), (c), 0, 0, 0)
#define MFMA32(a, b, c) __builtin_amdgcn_mfma_f32_32x32x16_bf16((a), (b), (c), 0, 0, 0)

static __device__ __forceinline__ unsigned short f2bf_u(float x) {
  __hip_bfloat16 h = __float2bfloat16(x);
  return *reinterpret_cast<unsigned short*>(&h);
}
static __device__ __forceinline__ float bfu2f(unsigned short u) {
  __hip_bfloat16 h;
  *reinterpret_cast<unsigned short*>(&h) = u;
  return __bfloat162float(h);
}
// 8 fp32 -> hi/lo bf16x8
static __device__ __forceinline__ void cvt8(f32x4 v0, f32x4 v1, bf16x8& h, bf16x8& l) {
#pragma unroll
  for (int j = 0; j < 4; j++) {
    unsigned short hu = f2bf_u(v0[j]);
    h[j] = (short)hu; l[j] = (short)f2bf_u(v0[j] - bfu2f(hu));
    hu = f2bf_u(v1[j]);
    h[j + 4] = (short)hu; l[j + 4] = (short)f2bf_u(v1[j] - bfu2f(hu));
  }
}
static __device__ __forceinline__ void cvt8h(f32x4 v0, f32x4 v1, bf16x8& h) {
#pragma unroll
  for (int j = 0; j < 4; j++) {
    h[j] = (short)f2bf_u(v0[j]);
    h[j + 4] = (short)f2bf_u(v1[j]);
  }
}

// fp32 -> (hi, lo) bf16 planes (W matrices only; 4 MB each).
__global__ __launch_bounds__(256) void split_kernel(
    const float* __restrict__ in, unsigned short* __restrict__ hi,
    unsigned short* __restrict__ lo, int n4) {
  int i = blockIdx.x * 256 + threadIdx.x;
  const int stride = gridDim.x * 256;
  for (; i < n4; i += stride) {
    f32x4 v = reinterpret_cast<const f32x4*>(in)[i];
    us4 h, l;
#pragma unroll
    for (int j = 0; j < 4; j++) {
      unsigned short hu = f2bf_u(v[j]);
      h[j] = hu;
      l[j] = f2bf_u(v[j] - bfu2f(hu));
    }
    reinterpret_cast<us4*>(hi)[i] = h;
    reinterpret_cast<us4*>(lo)[i] = l;
  }
}

// Q/K projection: 16m x 1024n per block (X read ONCE per kernel).
// 8 waves, wave w -> n in [w*128, +128). 3-pass split-bf16.
// Output: tiled hi/lo planes.
__global__ __launch_bounds__(512, 4) void proj_qk_kernel(
    const float* __restrict__ X,
    const unsigned short* __restrict__ Wh, const unsigned short* __restrict__ Wl,
    const float* __restrict__ bias,
    unsigned short* __restrict__ Oh, unsigned short* __restrict__ Ol) {
  const int tid = threadIdx.x;
  const int lane = tid & 63;
  const int wid = tid >> 6;
  const int lrow = lane & 15;
  const int kg = lane >> 4;
  const int bm = blockIdx.x * 16;

  const float* xrow = X + (size_t)(bm + lrow) * 1024 + kg * 8;
  const unsigned short* wb = (const unsigned short*)0;
  const size_t wbase = (size_t)(wid * 128 + lrow) * 1024 + kg * 8;

  f32x4 acc[8];
#pragma unroll
  for (int c = 0; c < 8; c++) acc[c] = f32x4{0.f, 0.f, 0.f, 0.f};

  for (int k = 0; k < 1024; k += 32) {
    f32x4 x0 = *(const f32x4*)(xrow + k);
    f32x4 x1 = *(const f32x4*)(xrow + k + 4);
    bf16x8 ah, al;
    cvt8(x0, x1, ah, al);
#pragma unroll
    for (int cf = 0; cf < 8; cf++) {
      const size_t wo = wbase + (size_t)cf * 16 * 1024 + k;
      bf16x8 bh = *(const bf16x8*)(Wh + wo);
      bf16x8 bl = *(const bf16x8*)(Wl + wo);
      acc[cf] = MFMA16(ah, bh, acc[cf]);
      acc[cf] = MFMA16(ah, bl, acc[cf]);
      acc[cf] = MFMA16(al, bh, acc[cf]);
    }
  }

  // Tiled store. C frag: col n (lane&15), rows m0 = bm + kg*4 + i.
  const int b = bm >> 11;
  const int sl = bm & 2047;
  const int g = sl >> 5;
  const int srow0 = (sl & 31) + kg * 4;
#pragma unroll
  for (int cf = 0; cf < 8; cf++) {
    const int n = wid * 128 + cf * 16 + lrow;
    const float bv = bias[n];
    const size_t tb = ((size_t)(b * 64 + g) * 64 + (n >> 4)) * 512 + (n & 15);
#pragma unroll
    for (int i = 0; i < 4; i++) {
      float val = acc[cf][i] + bv;
      unsigned short hu = f2bf_u(val);
      const size_t a = tb + (size_t)(srow0 + i) * 16;
      Oh[a] = hu;
      Ol[a] = f2bf_u(val - bfu2f(hu));
    }
  }
}

// V projection: 1-pass bf16, output tiled-transposed Vt[b][d/32][k/16][32][16].
__global__ __launch_bounds__(512, 4) void proj_v_kernel(
    const float* __restrict__ X, const unsigned short* __restrict__ Wh,
    const float* __restrict__ bias, unsigned short* __restrict__ Vt) {
  const int tid = threadIdx.x;
  const int lane = tid & 63;
  const int wid = tid >> 6;
  const int lrow = lane & 15;
  const int kg = lane >> 4;
  const int bm = blockIdx.x * 16;

  const float* xrow = X + (size_t)(bm + lrow) * 1024 + kg * 8;
  const size_t wbase = (size_t)(wid * 128 + lrow) * 1024 + kg * 8;

  f32x4 acc[8];
#pragma unroll
  for (int c = 0; c < 8; c++) acc[c] = f32x4{0.f, 0.f, 0.f, 0.f};

  for (int k = 0; k < 1024; k += 32) {
    f32x4 x0 = *(const f32x4*)(xrow + k);
    f32x4 x1 = *(const f32x4*)(xrow + k + 4);
    bf16x8 ah;
    cvt8h(x0, x1, ah);
#pragma unroll
    for (int cf = 0; cf < 8; cf++) {
      bf16x8 bh = *(const bf16x8*)(Wh + wbase + (size_t)cf * 16 * 1024 + k);
      acc[cf] = MFMA16(ah, bh, acc[cf]);
    }
  }

  const int b = bm >> 11;
  const int sl = bm & 2047;  // k-axis local
#pragma unroll
  for (int cf = 0; cf < 8; cf++) {
    const int d = wid * 128 + cf * 16 + lrow;
    const float bv = bias[d];
    us4 pk;
#pragma unroll
    for (int i = 0; i < 4; i++) pk[i] = f2bf_u(acc[cf][i] + bv);
    const size_t a = ((size_t)(b * 32 + (d >> 5)) * 128 + (sl >> 4)) * 512 +
                     (size_t)(d & 31) * 16 + kg * 4;
    *reinterpret_cast<us4*>(&Vt[a]) = pk;
  }
}

// attn: one block per (batch, 32 q-rows); 16 waves / 1024 threads.
// Wave w owns k-rows [w*128, +128) in QK^T and d-cols [w*64, +64) in PV.
// S^T in registers (4 x f32x16); exact softmax; P bf16 in XOR-swizzled LDS.
__global__ __launch_bounds__(1024, 4) void attn_kernel(
    const unsigned short* __restrict__ Qh, const unsigned short* __restrict__ Ql,
    const unsigned short* __restrict__ Kh, const unsigned short* __restrict__ Kl,
    const unsigned short* __restrict__ Vt, float* __restrict__ out) {
  __shared__ unsigned short P[32 * 2048];  // 128 KB
  __shared__ float redM[16][32];
  __shared__ float redS[16][32];
  __shared__ float rowinv[32];

  const int tid = threadIdx.x;
  const int lane = tid & 63;
  const int wid = tid >> 6;  // 0..15
  const int lq = lane & 31;
  const int hi = lane >> 5;

  // XCD-pinned decode: xcd = id%8 owns batch b = xcd>>1.
  const int id = blockIdx.x;
  const int xcd = id & 7;
  const int b = xcd >> 1;
  const int qt = (xcd & 1) + ((id >> 3) << 1);  // 0..63
  const int q0 = qt * 32;

  // ---- Phase 1: S^T[k 128][q 32] per wave, registers ----
  f32x16 acc0, acc1, acc2, acc3;
#pragma unroll
  for (int r = 0; r < 16; r++) { acc0[r] = 0.f; acc1[r] = 0.f; acc2[r] = 0.f; acc3[r] = 0.f; }

  const size_t lo16 = (size_t)lq * 16 + hi * 8;
  const unsigned short* qbh = Qh + ((size_t)(b * 64 + qt) * 64) * 512 + lo16;
  const unsigned short* qbl = Ql + ((size_t)(b * 64 + qt) * 64) * 512 + lo16;
  const unsigned short* kbh = Kh + ((size_t)(b * 64 + wid * 4) * 64) * 512 + lo16;
  const unsigned short* kbl = Kl + ((size_t)(b * 64 + wid * 4) * 64) * 512 + lo16;

  for (int kk = 0; kk < 64; kk++) {
    const size_t o = (size_t)kk * 512;
    bf16x8 qh = *(const bf16x8*)(qbh + o);
    bf16x8 ql = *(const bf16x8*)(qbl + o);
#define QK_STEP(GG, ACC)                                                   \
    {                                                                      \
      bf16x8 kh = *(const bf16x8*)(kbh + (size_t)(GG)*64 * 512 + o);       \
      bf16x8 kl = *(const bf16x8*)(kbl + (size_t)(GG)*64 * 512 + o);       \
      ACC = MFMA32(kh, qh, ACC);                                           \
      ACC = MFMA32(kl, qh, ACC);                                           \
      ACC = MFMA32(kh, ql, ACC);                                           \
    }
    QK_STEP(0, acc0)
    QK_STEP(1, acc1)
    QK_STEP(2, acc2)
    QK_STEP(3, acc3)
#undef QK_STEP
  }

  // ---- Phase 2: softmax ----
  float m = -3.0e38f;
#pragma unroll
  for (int r = 0; r < 16; r++) {
    m = fmaxf(m, fmaxf(fmaxf(acc0[r], acc1[r]), fmaxf(acc2[r], acc3[r])));
  }
  m = fmaxf(m, __shfl_xor(m, 32));
  if (hi == 0) redM[wid][lq] = m;
  __syncthreads();
  float M = redM[0][lq];
#pragma unroll
  for (int w = 1; w < 16; w++) M = fmaxf(M, redM[w][lq]);

  float s = 0.f;
#pragma unroll
  for (int r = 0; r < 16; r++) {
    acc0[r] = __expf(acc0[r] - M); s += acc0[r];
    acc1[r] = __expf(acc1[r] - M); s += acc1[r];
    acc2[r] = __expf(acc2[r] - M); s += acc2[r];
    acc3[r] = __expf(acc3[r] - M); s += acc3[r];
  }
  s += __shfl_xor(s, 32);
  if (hi == 0) redS[wid][lq] = s;
  __syncthreads();
  if (tid < 32) {
    float ss = 0.f;
#pragma unroll
    for (int w = 0; w < 16; w++) ss += redS[w][tid];
    rowinv[tid] = 1.0f / ss;
  }

  // ---- P -> bf16 LDS (XOR swizzle: elem idx ^= (lq&7)<<3) ----
  const int swz = (lq & 7) << 3;
  const int pb = lq * 2048 + wid * 128 + 4 * hi;
#define PWRITE(GG, ACC)                                                     \
  {                                                                         \
    _Pragma("unroll")                                                       \
    for (int qd = 0; qd < 4; qd++) {                                        \
      us4 pk;                                                               \
      _Pragma("unroll")                                                     \
      for (int i = 0; i < 4; i++) pk[i] = f2bf_u(ACC[qd * 4 + i]);          \
      *(us4*)&P[(pb + (GG)*32 + qd * 8) ^ swz] = pk;                        \
    }                                                                       \
  }
  PWRITE(0, acc0)
  PWRITE(1, acc1)
  PWRITE(2, acc2)
  PWRITE(3, acc3)
#undef PWRITE
  __syncthreads();

  // ---- Phase 3: O = P @ V (wave w: d in [w*64, +64)) ----
  f32x16 o0, o1;
#pragma unroll
  for (int r = 0; r < 16; r++) { o0[r] = 0.f; o1[r] = 0.f; }

  const unsigned short* vt0 = Vt + ((size_t)(b * 32 + wid * 2) * 128) * 512 + lo16;
  const unsigned short* vt1 = vt0 + (size_t)128 * 512;
  const int prow = lq * 2048 + hi * 8;
  for (int kk = 0; kk < 128; kk++) {
    bf16x8 pa = *(const bf16x8*)&P[(prow + kk * 16) ^ swz];
    bf16x8 v0 = *(const bf16x8*)(vt0 + (size_t)kk * 512);
    bf16x8 v1 = *(const bf16x8*)(vt1 + (size_t)kk * 512);
    o0 = MFMA32(pa, v0, o0);
    o1 = MFMA32(pa, v1, o1);
  }

  // ---- Epilogue ----
  float rv[16];
#pragma unroll
  for (int r = 0; r < 16; r++) rv[r] = rowinv[(r & 3) + 8 * (r >> 2) + 4 * hi];
  const int d0 = wid * 64 + lq;
#pragma unroll
  for (int r = 0; r < 16; r++) {
    const int q = (r & 3) + 8 * (r >> 2) + 4 * hi;
    const size_t ob = ((size_t)b * 2048 + q0 + q) * 1024;
    out[ob + d0] = o0[r] * rv[r];
    out[ob + d0 + 32] = o1[r] * rv[r];
  }
}

extern "C" void kernel_launch(void* const* d_in, const int* in_sizes, int n_in,
                              void* d_out, int out_size, void* d_ws, size_t ws_size,
                              hipStream_t stream) {
  const float* x  = (const float*)d_in[0];
  const float* Wq = (const float*)d_in[1];
  const float* bq = (const float*)d_in[2];
  const float* Wk = (const float*)d_in[3];
  const float* bk = (const float*)d_in[4];
  const float* Wv = (const float*)d_in[5];
  const float* bv = (const float*)d_in[6];
  float* o = (float*)d_out;

  const size_t NX = (size_t)8192 * 1024;
  const size_t NW = (size_t)1024 * 1024;
  unsigned short* p = (unsigned short*)d_ws;
  unsigned short* Qh = p; p += NX;
  unsigned short* Ql = p; p += NX;
  unsigned short* Kh = p; p += NX;
  unsigned short* Kl = p; p += NX;
  unsigned short* Vt = p; p += NX;
  unsigned short* Wqh = p; p += NW;
  unsigned short* Wql = p; p += NW;
  unsigned short* Wkh = p; p += NW;
  unsigned short* Wkl = p; p += NW;
  unsigned short* Wvh = p; p += NW;
  unsigned short* Wvl = p; p += NW;

  split_kernel<<<256, 256, 0, stream>>>(Wq, Wqh, Wql, (int)(NW / 4));
  split_kernel<<<256, 256, 0, stream>>>(Wk, Wkh, Wkl, (int)(NW / 4));
  split_kernel<<<256, 256, 0, stream>>>(Wv, Wvh, Wvl, (int)(NW / 4));

  proj_qk_kernel<<<512, 512, 0, stream>>>(x, Wqh, Wql, bq, Qh, Ql);
  proj_qk_kernel<<<512, 512, 0, stream>>>(x, Wkh, Wkl, bk, Kh, Kl);
  proj_v_kernel<<<512, 512, 0, stream>>>(x, Wvh, bv, Vt);

  attn_kernel<<<256, 1024, 0, stream>>>(Qh, Ql, Kh, Kl, Vt, o);
}

// Round 5
// 332.866 us; speedup vs baseline: 4.0342x; 2.4885x over previous
//
#include <hip/hip_runtime.h>
#include <hip/hip_bf16.h>

// B=4, S=2048, H=1024. Inputs/outputs fp32.
// Q/K: split-bf16 hi/lo 3-pass. V/PV: 1-pass bf16. Softmax fp32 exact.
// All GEMM operands in MFMA-fragment-native tiles:
//   Xt/Wt planes: [rows/16][k/32][512]; in-tile idx = l*8+j for lane l's
//     A/B fragment element (row=l&15, k=(l>>4)*8+j)   -- 16x16x32 shape
//   Q,K planes: [b][s/32][h/16][srow 32][h 16]        -- 32x32x16 A-op
//   Vt:         [b][d/32][k/16][in-tile (d&31)*16 + (k&15)]  -- 32x32x16 B-op
// ws (ushort): Xth Xtl Qh Ql Kh Kl Vt [8.39M each] + 6x W planes [1.05M] = 130MB

typedef __attribute__((ext_vector_type(4))) float f32x4;
typedef __attribute__((ext_vector_type(16))) float f32x16;
typedef __attribute__((ext_vector_type(8))) short bf16x8;
typedef __attribute__((ext_vector_type(4))) unsigned short us4;

#define MFMA16(a, b, c) __builtin_amdgcn_mfma_f32_16x16x32_bf16((a), (b), (c), 0, 0, 0)
#define MFMA32(a, b, c) __builtin_amdgcn_mfma_f32_32x32x16_bf16((a), (b), (c), 0, 0, 0)

static __device__ __forceinline__ unsigned short f2bf_u(float x) {
  __hip_bfloat16 h = __float2bfloat16(x);
  return *reinterpret_cast<unsigned short*>(&h);
}
static __device__ __forceinline__ float bfu2f(unsigned short u) {
  __hip_bfloat16 h;
  *reinterpret_cast<unsigned short*>(&h) = u;
  return __bfloat162float(h);
}
static __device__ __forceinline__ void cvt8(f32x4 v0, f32x4 v1, bf16x8& h, bf16x8& l) {
#pragma unroll
  for (int j = 0; j < 4; j++) {
    unsigned short hu = f2bf_u(v0[j]);
    h[j] = (short)hu; l[j] = (short)f2bf_u(v0[j] - bfu2f(hu));
    hu = f2bf_u(v1[j]);
    h[j + 4] = (short)hu; l[j + 4] = (short)f2bf_u(v1[j] - bfu2f(hu));
  }
}

// fp32 [rows][1024] -> hi/lo bf16 fragment tiles [rows/16][32][512].
// One thread = one lane-slot of one tile (8 contiguous ushorts out).
__global__ __launch_bounds__(256) void split_tiled_kernel(
    const float* __restrict__ in, unsigned short* __restrict__ hi,
    unsigned short* __restrict__ lo, int ntiles) {
  const int t = blockIdx.x * 256 + threadIdx.x;
  if (t >= ntiles * 64) return;
  const int tile = t >> 6;
  const int l = t & 63;
  const int mt = tile >> 5;
  const int kt = tile & 31;
  const int m = mt * 16 + (l & 15);
  const int kb = kt * 32 + (l >> 4) * 8;
  const float* src = in + (size_t)m * 1024 + kb;
  f32x4 v0 = *(const f32x4*)src;
  f32x4 v1 = *(const f32x4*)(src + 4);
  bf16x8 h, lv;
  cvt8(v0, v1, h, lv);
  *(bf16x8*)(hi + (size_t)tile * 512 + l * 8) = h;
  *(bf16x8*)(lo + (size_t)tile * 512 + l * 8) = lv;
}

// Q/K projection, 3-pass split-bf16, all-coalesced tiled operands.
// Block: 32 m x 512 n (grid 256 x 2), 8 waves; wave -> 4 n-tiles.
__global__ __launch_bounds__(512, 2) void proj_qk_kernel(
    const unsigned short* __restrict__ Xth, const unsigned short* __restrict__ Xtl,
    const unsigned short* __restrict__ Wth, const unsigned short* __restrict__ Wtl,
    const float* __restrict__ bias,
    unsigned short* __restrict__ Oh, unsigned short* __restrict__ Ol) {
  const int tid = threadIdx.x;
  const int lane = tid & 63;
  const int wid = tid >> 6;
  const int lrow = lane & 15;
  const int kg = lane >> 4;
  const int bx = blockIdx.x;      // m-tile32 index, 0..255
  const int ntb = blockIdx.y * 32 + wid * 4;

  const unsigned short* xh = Xth + (size_t)(bx * 2) * 32 * 512 + lane * 8;
  const unsigned short* xl = Xtl + (size_t)(bx * 2) * 32 * 512 + lane * 8;

  f32x4 acc[2][4];
#pragma unroll
  for (int mf = 0; mf < 2; mf++)
#pragma unroll
    for (int cf = 0; cf < 4; cf++) acc[mf][cf] = f32x4{0.f, 0.f, 0.f, 0.f};

  for (int kt = 0; kt < 32; kt++) {
    const size_t o = (size_t)kt * 512;
    bf16x8 a0h = *(const bf16x8*)(xh + o);
    bf16x8 a0l = *(const bf16x8*)(xl + o);
    bf16x8 a1h = *(const bf16x8*)(xh + 32 * 512 + o);
    bf16x8 a1l = *(const bf16x8*)(xl + 32 * 512 + o);
#pragma unroll
    for (int cf = 0; cf < 4; cf++) {
      const size_t wo = ((size_t)(ntb + cf) * 32 + kt) * 512 + lane * 8;
      bf16x8 bh = *(const bf16x8*)(Wth + wo);
      bf16x8 bl = *(const bf16x8*)(Wtl + wo);
      acc[0][cf] = MFMA16(a0h, bh, acc[0][cf]);
      acc[0][cf] = MFMA16(a0h, bl, acc[0][cf]);
      acc[0][cf] = MFMA16(a0l, bh, acc[0][cf]);
      acc[1][cf] = MFMA16(a1h, bh, acc[1][cf]);
      acc[1][cf] = MFMA16(a1h, bl, acc[1][cf]);
      acc[1][cf] = MFMA16(a1l, bh, acc[1][cf]);
    }
  }

  // Store tiled Q/K: [b][s/32][h/16][srow*16 + (n&15)]
  const int b = bx >> 6;
  const int st = bx & 63;
#pragma unroll
  for (int mf = 0; mf < 2; mf++) {
#pragma unroll
    for (int cf = 0; cf < 4; cf++) {
      const int nt = ntb + cf;
      const int n = nt * 16 + lrow;
      const float bv = bias[n];
      const size_t base = ((size_t)((b * 64 + st) * 64 + nt)) * 512 + lrow;
      const int srow0 = mf * 16 + kg * 4;
#pragma unroll
      for (int i = 0; i < 4; i++) {
        float val = acc[mf][cf][i] + bv;
        unsigned short hu = f2bf_u(val);
        const size_t a = base + (size_t)(srow0 + i) * 16;
        Oh[a] = hu;
        Ol[a] = f2bf_u(val - bfu2f(hu));
      }
    }
  }
}

// V projection, 1-pass bf16, tiled operands; Vt output in attn B-op tiles.
__global__ __launch_bounds__(512, 2) void proj_v_kernel(
    const unsigned short* __restrict__ Xth, const unsigned short* __restrict__ Wth,
    const float* __restrict__ bias, unsigned short* __restrict__ Vt) {
  const int tid = threadIdx.x;
  const int lane = tid & 63;
  const int wid = tid >> 6;
  const int lrow = lane & 15;
  const int kg = lane >> 4;
  const int bx = blockIdx.x;
  const int ntb = blockIdx.y * 32 + wid * 4;

  const unsigned short* xh = Xth + (size_t)(bx * 2) * 32 * 512 + lane * 8;

  f32x4 acc[2][4];
#pragma unroll
  for (int mf = 0; mf < 2; mf++)
#pragma unroll
    for (int cf = 0; cf < 4; cf++) acc[mf][cf] = f32x4{0.f, 0.f, 0.f, 0.f};

  for (int kt = 0; kt < 32; kt++) {
    const size_t o = (size_t)kt * 512;
    bf16x8 a0h = *(const bf16x8*)(xh + o);
    bf16x8 a1h = *(const bf16x8*)(xh + 32 * 512 + o);
#pragma unroll
    for (int cf = 0; cf < 4; cf++) {
      const size_t wo = ((size_t)(ntb + cf) * 32 + kt) * 512 + lane * 8;
      bf16x8 bh = *(const bf16x8*)(Wth + wo);
      acc[0][cf] = MFMA16(a0h, bh, acc[0][cf]);
      acc[1][cf] = MFMA16(a1h, bh, acc[1][cf]);
    }
  }

  // Store Vt[b][d/32][k/16][(d&31)*16 + (k&15)]; C rows are the key axis.
  const int b = bx >> 6;
#pragma unroll
  for (int mf = 0; mf < 2; mf++) {
    const int kl_hi = (bx & 63) * 2 + mf;  // k_local >> 4
#pragma unroll
    for (int cf = 0; cf < 4; cf++) {
      const int d = (ntb + cf) * 16 + lrow;
      const float bv = bias[d];
      us4 pk;
#pragma unroll
      for (int i = 0; i < 4; i++) pk[i] = f2bf_u(acc[mf][cf][i] + bv);
      const size_t a = ((size_t)(b * 32 + (d >> 5)) * 128 + kl_hi) * 512 +
                       (size_t)(d & 31) * 16 + kg * 4;
      *reinterpret_cast<us4*>(&Vt[a]) = pk;
    }
  }
}

// attn: one block per (batch, 32 q-rows); 16 waves / 1024 threads. (unchanged)
__global__ __launch_bounds__(1024, 4) void attn_kernel(
    const unsigned short* __restrict__ Qh, const unsigned short* __restrict__ Ql,
    const unsigned short* __restrict__ Kh, const unsigned short* __restrict__ Kl,
    const unsigned short* __restrict__ Vt, float* __restrict__ out) {
  __shared__ unsigned short P[32 * 2048];  // 128 KB
  __shared__ float redM[16][32];
  __shared__ float redS[16][32];
  __shared__ float rowinv[32];

  const int tid = threadIdx.x;
  const int lane = tid & 63;
  const int wid = tid >> 6;  // 0..15
  const int lq = lane & 31;
  const int hi = lane >> 5;

  const int id = blockIdx.x;
  const int xcd = id & 7;
  const int b = xcd >> 1;
  const int qt = (xcd & 1) + ((id >> 3) << 1);  // 0..63
  const int q0 = qt * 32;

  f32x16 acc0, acc1, acc2, acc3;
#pragma unroll
  for (int r = 0; r < 16; r++) { acc0[r] = 0.f; acc1[r] = 0.f; acc2[r] = 0.f; acc3[r] = 0.f; }

  const size_t lo16 = (size_t)lq * 16 + hi * 8;
  const unsigned short* qbh = Qh + ((size_t)(b * 64 + qt) * 64) * 512 + lo16;
  const unsigned short* qbl = Ql + ((size_t)(b * 64 + qt) * 64) * 512 + lo16;
  const unsigned short* kbh = Kh + ((size_t)(b * 64 + wid * 4) * 64) * 512 + lo16;
  const unsigned short* kbl = Kl + ((size_t)(b * 64 + wid * 4) * 64) * 512 + lo16;

  for (int kk = 0; kk < 64; kk++) {
    const size_t o = (size_t)kk * 512;
    bf16x8 qh = *(const bf16x8*)(qbh + o);
    bf16x8 ql = *(const bf16x8*)(qbl + o);
#define QK_STEP(GG, ACC)                                                   \
    {                                                                      \
      bf16x8 kh = *(const bf16x8*)(kbh + (size_t)(GG)*64 * 512 + o);       \
      bf16x8 kl = *(const bf16x8*)(kbl + (size_t)(GG)*64 * 512 + o);       \
      ACC = MFMA32(kh, qh, ACC);                                           \
      ACC = MFMA32(kl, qh, ACC);                                           \
      ACC = MFMA32(kh, ql, ACC);                                           \
    }
    QK_STEP(0, acc0)
    QK_STEP(1, acc1)
    QK_STEP(2, acc2)
    QK_STEP(3, acc3)
#undef QK_STEP
  }

  float m = -3.0e38f;
#pragma unroll
  for (int r = 0; r < 16; r++) {
    m = fmaxf(m, fmaxf(fmaxf(acc0[r], acc1[r]), fmaxf(acc2[r], acc3[r])));
  }
  m = fmaxf(m, __shfl_xor(m, 32));
  if (hi == 0) redM[wid][lq] = m;
  __syncthreads();
  float M = redM[0][lq];
#pragma unroll
  for (int w = 1; w < 16; w++) M = fmaxf(M, redM[w][lq]);

  float s = 0.f;
#pragma unroll
  for (int r = 0; r < 16; r++) {
    acc0[r] = __expf(acc0[r] - M); s += acc0[r];
    acc1[r] = __expf(acc1[r] - M); s += acc1[r];
    acc2[r] = __expf(acc2[r] - M); s += acc2[r];
    acc3[r] = __expf(acc3[r] - M); s += acc3[r];
  }
  s += __shfl_xor(s, 32);
  if (hi == 0) redS[wid][lq] = s;
  __syncthreads();
  if (tid < 32) {
    float ss = 0.f;
#pragma unroll
    for (int w = 0; w < 16; w++) ss += redS[w][tid];
    rowinv[tid] = 1.0f / ss;
  }

  const int swz = (lq & 7) << 3;
  const int pb = lq * 2048 + wid * 128 + 4 * hi;
#define PWRITE(GG, ACC)                                                     \
  {                                                                         \
    _Pragma("unroll")                                                       \
    for (int qd = 0; qd < 4; qd++) {                                        \
      us4 pk;                                                               \
      _Pragma("unroll")                                                     \
      for (int i = 0; i < 4; i++) pk[i] = f2bf_u(ACC[qd * 4 + i]);          \
      *(us4*)&P[(pb + (GG)*32 + qd * 8) ^ swz] = pk;                        \
    }                                                                       \
  }
  PWRITE(0, acc0)
  PWRITE(1, acc1)
  PWRITE(2, acc2)
  PWRITE(3, acc3)
#undef PWRITE
  __syncthreads();

  f32x16 o0, o1;
#pragma unroll
  for (int r = 0; r < 16; r++) { o0[r] = 0.f; o1[r] = 0.f; }

  const unsigned short* vt0 = Vt + ((size_t)(b * 32 + wid * 2) * 128) * 512 + lo16;
  const unsigned short* vt1 = vt0 + (size_t)128 * 512;
  const int prow = lq * 2048 + hi * 8;
  for (int kk = 0; kk < 128; kk++) {
    bf16x8 pa = *(const bf16x8*)&P[(prow + kk * 16) ^ swz];
    bf16x8 v0 = *(const bf16x8*)(vt0 + (size_t)kk * 512);
    bf16x8 v1 = *(const bf16x8*)(vt1 + (size_t)kk * 512);
    o0 = MFMA32(pa, v0, o0);
    o1 = MFMA32(pa, v1, o1);
  }

  float rv[16];
#pragma unroll
  for (int r = 0; r < 16; r++) rv[r] = rowinv[(r & 3) + 8 * (r >> 2) + 4 * hi];
  const int d0 = wid * 64 + lq;
#pragma unroll
  for (int r = 0; r < 16; r++) {
    const int q = (r & 3) + 8 * (r >> 2) + 4 * hi;
    const size_t ob = ((size_t)b * 2048 + q0 + q) * 1024;
    out[ob + d0] = o0[r] * rv[r];
    out[ob + d0 + 32] = o1[r] * rv[r];
  }
}

extern "C" void kernel_launch(void* const* d_in, const int* in_sizes, int n_in,
                              void* d_out, int out_size, void* d_ws, size_t ws_size,
                              hipStream_t stream) {
  const float* x  = (const float*)d_in[0];
  const float* Wq = (const float*)d_in[1];
  const float* bq = (const float*)d_in[2];
  const float* Wk = (const float*)d_in[3];
  const float* bk = (const float*)d_in[4];
  const float* Wv = (const float*)d_in[5];
  const float* bv = (const float*)d_in[6];
  float* o = (float*)d_out;

  const size_t NX = (size_t)8192 * 1024;
  const size_t NW = (size_t)1024 * 1024;
  unsigned short* p = (unsigned short*)d_ws;
  unsigned short* Xth = p; p += NX;
  unsigned short* Xtl = p; p += NX;
  unsigned short* Qh = p; p += NX;
  unsigned short* Ql = p; p += NX;
  unsigned short* Kh = p; p += NX;
  unsigned short* Kl = p; p += NX;
  unsigned short* Vt = p; p += NX;
  unsigned short* Wqh = p; p += NW;
  unsigned short* Wql = p; p += NW;
  unsigned short* Wkh = p; p += NW;
  unsigned short* Wkl = p; p += NW;
  unsigned short* Wvh = p; p += NW;
  unsigned short* Wvl = p; p += NW;

  split_tiled_kernel<<<4096, 256, 0, stream>>>(x, Xth, Xtl, 16384);
  split_tiled_kernel<<<512, 256, 0, stream>>>(Wq, Wqh, Wql, 2048);
  split_tiled_kernel<<<512, 256, 0, stream>>>(Wk, Wkh, Wkl, 2048);
  split_tiled_kernel<<<512, 256, 0, stream>>>(Wv, Wvh, Wvl, 2048);

  dim3 gp(256, 2), bp(512);
  proj_qk_kernel<<<gp, bp, 0, stream>>>(Xth, Xtl, Wqh, Wql, bq, Qh, Ql);
  proj_qk_kernel<<<gp, bp, 0, stream>>>(Xth, Xtl, Wkh, Wkl, bk, Kh, Kl);
  proj_v_kernel<<<gp, bp, 0, stream>>>(Xth, Wvh, bv, Vt);

  attn_kernel<<<256, 1024, 0, stream>>>(Qh, Ql, Kh, Kl, Vt, o);
}

// Round 6
// 302.014 us; speedup vs baseline: 4.4464x; 1.1022x over previous
//
#include <hip/hip_runtime.h>
#include <hip/hip_bf16.h>

// B=4, S=2048, H=1024. Inputs/outputs fp32.
// Q/K: split-bf16 hi/lo 3-pass. V/PV: 1-pass bf16. Softmax fp32 exact.
// All GEMM operands in MFMA-fragment-native tiles:
//   Xt/Wt planes: [rows/16][k/32][512]; lane l's 8 elems at tile+l*8
//   Q,K planes: [b][s/32][h/16][srow 32][h 16]
//   Vt:         [b][d/32][k/16][(d&31)*16 + (k&15)]
// ws (ushort): Xth Xtl Qh Ql Kh Kl Vt [8.39M each] + 6x W planes [1.05M] = 130MB

typedef __attribute__((ext_vector_type(4))) float f32x4;
typedef __attribute__((ext_vector_type(16))) float f32x16;
typedef __attribute__((ext_vector_type(8))) short bf16x8;
typedef __attribute__((ext_vector_type(4))) unsigned short us4;

#define MFMA16(a, b, c) __builtin_amdgcn_mfma_f32_16x16x32_bf16((a), (b), (c), 0, 0, 0)
#define MFMA32(a, b, c) __builtin_amdgcn_mfma_f32_32x32x16_bf16((a), (b), (c), 0, 0, 0)

static __device__ __forceinline__ unsigned short f2bf_u(float x) {
  __hip_bfloat16 h = __float2bfloat16(x);
  return *reinterpret_cast<unsigned short*>(&h);
}
static __device__ __forceinline__ float bfu2f(unsigned short u) {
  __hip_bfloat16 h;
  *reinterpret_cast<unsigned short*>(&h) = u;
  return __bfloat162float(h);
}
static __device__ __forceinline__ void cvt8(f32x4 v0, f32x4 v1, bf16x8& h, bf16x8& l) {
#pragma unroll
  for (int j = 0; j < 4; j++) {
    unsigned short hu = f2bf_u(v0[j]);
    h[j] = (short)hu; l[j] = (short)f2bf_u(v0[j] - bfu2f(hu));
    hu = f2bf_u(v1[j]);
    h[j + 4] = (short)hu; l[j + 4] = (short)f2bf_u(v1[j] - bfu2f(hu));
  }
}

// fp32 [rows][1024] -> hi/lo bf16 fragment tiles [rows/16][32][512].
__global__ __launch_bounds__(256) void split_tiled_kernel(
    const float* __restrict__ in, unsigned short* __restrict__ hi,
    unsigned short* __restrict__ lo, int ntiles) {
  const int t = blockIdx.x * 256 + threadIdx.x;
  if (t >= ntiles * 64) return;
  const int tile = t >> 6;
  const int l = t & 63;
  const int mt = tile >> 5;
  const int kt = tile & 31;
  const int m = mt * 16 + (l & 15);
  const int kb = kt * 32 + (l >> 4) * 8;
  const float* src = in + (size_t)m * 1024 + kb;
  f32x4 v0 = *(const f32x4*)src;
  f32x4 v1 = *(const f32x4*)(src + 4);
  bf16x8 h, lv;
  cvt8(v0, v1, h, lv);
  *(bf16x8*)(hi + (size_t)tile * 512 + l * 8) = h;
  *(bf16x8*)(lo + (size_t)tile * 512 + l * 8) = lv;
}

// All three W splits in one dispatch (blockIdx.y selects matrix).
__global__ __launch_bounds__(256) void split3_kernel(
    const float* __restrict__ w0, const float* __restrict__ w1,
    const float* __restrict__ w2,
    unsigned short* __restrict__ h0, unsigned short* __restrict__ l0,
    unsigned short* __restrict__ h1, unsigned short* __restrict__ l1,
    unsigned short* __restrict__ h2, unsigned short* __restrict__ l2) {
  const int which = blockIdx.y;
  const float* in = which == 0 ? w0 : (which == 1 ? w1 : w2);
  unsigned short* hi = which == 0 ? h0 : (which == 1 ? h1 : h2);
  unsigned short* lo = which == 0 ? l0 : (which == 1 ? l1 : l2);
  const int t = blockIdx.x * 256 + threadIdx.x;
  const int tile = t >> 6;
  const int l = t & 63;
  const int mt = tile >> 5;
  const int kt = tile & 31;
  const int m = mt * 16 + (l & 15);
  const int kb = kt * 32 + (l >> 4) * 8;
  const float* src = in + (size_t)m * 1024 + kb;
  f32x4 v0 = *(const f32x4*)src;
  f32x4 v1 = *(const f32x4*)(src + 4);
  bf16x8 h, lv;
  cvt8(v0, v1, h, lv);
  *(bf16x8*)(hi + (size_t)tile * 512 + l * 8) = h;
  *(bf16x8*)(lo + (size_t)tile * 512 + l * 8) = lv;
}

// Fused Q/K/V projection. Block: 64 m x 512 n; grid (128, 2, 3); z slowest
// so the three phases stay temporally separated (W L2-residency).
// z=0: Q (3-pass, tiled hi/lo store). z=1: K. z=2: V (1-pass, Vt store).
__global__ __launch_bounds__(512, 2) void proj_fused_kernel(
    const unsigned short* __restrict__ Xth, const unsigned short* __restrict__ Xtl,
    const unsigned short* __restrict__ Wqh, const unsigned short* __restrict__ Wql,
    const unsigned short* __restrict__ Wkh, const unsigned short* __restrict__ Wkl,
    const unsigned short* __restrict__ Wvh,
    const float* __restrict__ bq, const float* __restrict__ bk,
    const float* __restrict__ bv,
    unsigned short* __restrict__ Qh, unsigned short* __restrict__ Ql,
    unsigned short* __restrict__ Kh, unsigned short* __restrict__ Kl,
    unsigned short* __restrict__ Vt) {
  const int tid = threadIdx.x;
  const int lane = tid & 63;
  const int wid = tid >> 6;
  const int lrow = lane & 15;
  const int kg = lane >> 4;
  const int bx = blockIdx.x;               // 64-row m-block, 0..127
  const int ntb = blockIdx.y * 32 + wid * 4;
  const int z = blockIdx.z;

  const unsigned short* Wh = z == 0 ? Wqh : (z == 1 ? Wkh : Wvh);
  const unsigned short* Wl = z == 0 ? Wql : Wkl;  // unused for z==2
  const float* bias = z == 0 ? bq : (z == 1 ? bk : bv);

  const unsigned short* xh = Xth + (size_t)(bx * 4) * 32 * 512 + lane * 8;
  const unsigned short* xl = Xtl + (size_t)(bx * 4) * 32 * 512 + lane * 8;

  f32x4 acc[4][4];
#pragma unroll
  for (int mf = 0; mf < 4; mf++)
#pragma unroll
    for (int cf = 0; cf < 4; cf++) acc[mf][cf] = f32x4{0.f, 0.f, 0.f, 0.f};

  if (z < 2) {
    for (int kt = 0; kt < 32; kt++) {
      const size_t o = (size_t)kt * 512;
      bf16x8 ah[4], al[4];
#pragma unroll
      for (int mf = 0; mf < 4; mf++) {
        ah[mf] = *(const bf16x8*)(xh + (size_t)mf * 32 * 512 + o);
        al[mf] = *(const bf16x8*)(xl + (size_t)mf * 32 * 512 + o);
      }
#pragma unroll
      for (int cf = 0; cf < 4; cf++) {
        const size_t wo = ((size_t)(ntb + cf) * 32 + kt) * 512 + lane * 8;
        bf16x8 bh = *(const bf16x8*)(Wh + wo);
        bf16x8 bl = *(const bf16x8*)(Wl + wo);
#pragma unroll
        for (int mf = 0; mf < 4; mf++) {
          acc[mf][cf] = MFMA16(ah[mf], bh, acc[mf][cf]);
          acc[mf][cf] = MFMA16(ah[mf], bl, acc[mf][cf]);
          acc[mf][cf] = MFMA16(al[mf], bh, acc[mf][cf]);
        }
      }
    }
    unsigned short* Oh = z == 0 ? Qh : Kh;
    unsigned short* Ol = z == 0 ? Ql : Kl;
    const int b = bx >> 5;
#pragma unroll
    for (int mf = 0; mf < 4; mf++) {
      const int st = (bx & 31) * 2 + (mf >> 1);
      const int srow0 = (mf & 1) * 16 + kg * 4;
#pragma unroll
      for (int cf = 0; cf < 4; cf++) {
        const int nt = ntb + cf;
        const float bv_ = bias[nt * 16 + lrow];
        const size_t base = ((size_t)((b * 64 + st) * 64 + nt)) * 512 + lrow;
#pragma unroll
        for (int i = 0; i < 4; i++) {
          float val = acc[mf][cf][i] + bv_;
          unsigned short hu = f2bf_u(val);
          const size_t a = base + (size_t)(srow0 + i) * 16;
          Oh[a] = hu;
          Ol[a] = f2bf_u(val - bfu2f(hu));
        }
      }
    }
  } else {
    for (int kt = 0; kt < 32; kt++) {
      const size_t o = (size_t)kt * 512;
      bf16x8 ah[4];
#pragma unroll
      for (int mf = 0; mf < 4; mf++)
        ah[mf] = *(const bf16x8*)(xh + (size_t)mf * 32 * 512 + o);
#pragma unroll
      for (int cf = 0; cf < 4; cf++) {
        const size_t wo = ((size_t)(ntb + cf) * 32 + kt) * 512 + lane * 8;
        bf16x8 bh = *(const bf16x8*)(Wh + wo);
#pragma unroll
        for (int mf = 0; mf < 4; mf++) acc[mf][cf] = MFMA16(ah[mf], bh, acc[mf][cf]);
      }
    }
    const int b = bx >> 5;
#pragma unroll
    for (int mf = 0; mf < 4; mf++) {
      const int kl_hi = (bx & 31) * 4 + mf;  // (k_local)>>4
#pragma unroll
      for (int cf = 0; cf < 4; cf++) {
        const int d = (ntb + cf) * 16 + lrow;
        const float bv_ = bias[d];
        us4 pk;
#pragma unroll
        for (int i = 0; i < 4; i++) pk[i] = f2bf_u(acc[mf][cf][i] + bv_);
        const size_t a = ((size_t)(b * 32 + (d >> 5)) * 128 + kl_hi) * 512 +
                         (size_t)(d & 31) * 16 + kg * 4;
        *reinterpret_cast<us4*>(&Vt[a]) = pk;
      }
    }
  }
}

// attn: one block per (batch, 32 q-rows); 16 waves / 1024 threads.
// QK^T split into two k-sweeps so each streamed plane (K-hi, then K-lo)
// fits the per-XCD L2 (4.2 MB/batch). s_setprio around MFMA clusters.
__global__ __launch_bounds__(1024, 4) void attn_kernel(
    const unsigned short* __restrict__ Qh, const unsigned short* __restrict__ Ql,
    const unsigned short* __restrict__ Kh, const unsigned short* __restrict__ Kl,
    const unsigned short* __restrict__ Vt, float* __restrict__ out) {
  __shared__ unsigned short P[32 * 2048];  // 128 KB
  __shared__ float redM[16][32];
  __shared__ float redS[16][32];
  __shared__ float rowinv[32];

  const int tid = threadIdx.x;
  const int lane = tid & 63;
  const int wid = tid >> 6;  // 0..15
  const int lq = lane & 31;
  const int hi = lane >> 5;

  const int id = blockIdx.x;
  const int xcd = id & 7;
  const int b = xcd >> 1;
  const int qt = (xcd & 1) + ((id >> 3) << 1);  // 0..63
  const int q0 = qt * 32;

  f32x16 acc0, acc1, acc2, acc3;
#pragma unroll
  for (int r = 0; r < 16; r++) { acc0[r] = 0.f; acc1[r] = 0.f; acc2[r] = 0.f; acc3[r] = 0.f; }

  const size_t lo16 = (size_t)lq * 16 + hi * 8;
  const unsigned short* qbh = Qh + ((size_t)(b * 64 + qt) * 64) * 512 + lo16;
  const unsigned short* qbl = Ql + ((size_t)(b * 64 + qt) * 64) * 512 + lo16;
  const unsigned short* kbh = Kh + ((size_t)(b * 64 + wid * 4) * 64) * 512 + lo16;
  const unsigned short* kbl = Kl + ((size_t)(b * 64 + wid * 4) * 64) * 512 + lo16;

  // ---- Sweep A: K-hi stream (kh*qh + kh*ql) ----
  for (int kk = 0; kk < 64; kk++) {
    const size_t o = (size_t)kk * 512;
    bf16x8 qh = *(const bf16x8*)(qbh + o);
    bf16x8 ql = *(const bf16x8*)(qbl + o);
    bf16x8 k0 = *(const bf16x8*)(kbh + (size_t)0 * 64 * 512 + o);
    bf16x8 k1 = *(const bf16x8*)(kbh + (size_t)1 * 64 * 512 + o);
    bf16x8 k2 = *(const bf16x8*)(kbh + (size_t)2 * 64 * 512 + o);
    bf16x8 k3 = *(const bf16x8*)(kbh + (size_t)3 * 64 * 512 + o);
    __builtin_amdgcn_s_setprio(1);
    acc0 = MFMA32(k0, qh, acc0);
    acc1 = MFMA32(k1, qh, acc1);
    acc2 = MFMA32(k2, qh, acc2);
    acc3 = MFMA32(k3, qh, acc3);
    acc0 = MFMA32(k0, ql, acc0);
    acc1 = MFMA32(k1, ql, acc1);
    acc2 = MFMA32(k2, ql, acc2);
    acc3 = MFMA32(k3, ql, acc3);
    __builtin_amdgcn_s_setprio(0);
  }
  // ---- Sweep B: K-lo stream (kl*qh) ----
  for (int kk = 0; kk < 64; kk++) {
    const size_t o = (size_t)kk * 512;
    bf16x8 qh = *(const bf16x8*)(qbh + o);
    bf16x8 k0 = *(const bf16x8*)(kbl + (size_t)0 * 64 * 512 + o);
    bf16x8 k1 = *(const bf16x8*)(kbl + (size_t)1 * 64 * 512 + o);
    bf16x8 k2 = *(const bf16x8*)(kbl + (size_t)2 * 64 * 512 + o);
    bf16x8 k3 = *(const bf16x8*)(kbl + (size_t)3 * 64 * 512 + o);
    __builtin_amdgcn_s_setprio(1);
    acc0 = MFMA32(k0, qh, acc0);
    acc1 = MFMA32(k1, qh, acc1);
    acc2 = MFMA32(k2, qh, acc2);
    acc3 = MFMA32(k3, qh, acc3);
    __builtin_amdgcn_s_setprio(0);
  }

  // ---- softmax (exact) ----
  float m = -3.0e38f;
#pragma unroll
  for (int r = 0; r < 16; r++) {
    m = fmaxf(m, fmaxf(fmaxf(acc0[r], acc1[r]), fmaxf(acc2[r], acc3[r])));
  }
  m = fmaxf(m, __shfl_xor(m, 32));
  if (hi == 0) redM[wid][lq] = m;
  __syncthreads();
  float M = redM[0][lq];
#pragma unroll
  for (int w = 1; w < 16; w++) M = fmaxf(M, redM[w][lq]);

  float s = 0.f;
#pragma unroll
  for (int r = 0; r < 16; r++) {
    acc0[r] = __expf(acc0[r] - M); s += acc0[r];
    acc1[r] = __expf(acc1[r] - M); s += acc1[r];
    acc2[r] = __expf(acc2[r] - M); s += acc2[r];
    acc3[r] = __expf(acc3[r] - M); s += acc3[r];
  }
  s += __shfl_xor(s, 32);
  if (hi == 0) redS[wid][lq] = s;
  __syncthreads();
  if (tid < 32) {
    float ss = 0.f;
#pragma unroll
    for (int w = 0; w < 16; w++) ss += redS[w][tid];
    rowinv[tid] = 1.0f / ss;
  }

  // ---- P -> bf16 LDS (XOR swizzle) ----
  const int swz = (lq & 7) << 3;
  const int pb = lq * 2048 + wid * 128 + 4 * hi;
#define PWRITE(GG, ACC)                                                     \
  {                                                                         \
    _Pragma("unroll")                                                       \
    for (int qd = 0; qd < 4; qd++) {                                        \
      us4 pk;                                                               \
      _Pragma("unroll")                                                     \
      for (int i = 0; i < 4; i++) pk[i] = f2bf_u(ACC[qd * 4 + i]);          \
      *(us4*)&P[(pb + (GG)*32 + qd * 8) ^ swz] = pk;                        \
    }                                                                       \
  }
  PWRITE(0, acc0)
  PWRITE(1, acc1)
  PWRITE(2, acc2)
  PWRITE(3, acc3)
#undef PWRITE
  __syncthreads();

  // ---- O = P @ V (V stream 4.2 MB/batch, L2-resident) ----
  f32x16 o0, o1;
#pragma unroll
  for (int r = 0; r < 16; r++) { o0[r] = 0.f; o1[r] = 0.f; }

  const unsigned short* vt0 = Vt + ((size_t)(b * 32 + wid * 2) * 128) * 512 + lo16;
  const unsigned short* vt1 = vt0 + (size_t)128 * 512;
  const int prow = lq * 2048 + hi * 8;
#pragma unroll 2
  for (int kk = 0; kk < 128; kk++) {
    bf16x8 pa = *(const bf16x8*)&P[(prow + kk * 16) ^ swz];
    bf16x8 v0 = *(const bf16x8*)(vt0 + (size_t)kk * 512);
    bf16x8 v1 = *(const bf16x8*)(vt1 + (size_t)kk * 512);
    __builtin_amdgcn_s_setprio(1);
    o0 = MFMA32(pa, v0, o0);
    o1 = MFMA32(pa, v1, o1);
    __builtin_amdgcn_s_setprio(0);
  }

  float rv[16];
#pragma unroll
  for (int r = 0; r < 16; r++) rv[r] = rowinv[(r & 3) + 8 * (r >> 2) + 4 * hi];
  const int d0 = wid * 64 + lq;
#pragma unroll
  for (int r = 0; r < 16; r++) {
    const int q = (r & 3) + 8 * (r >> 2) + 4 * hi;
    const size_t ob = ((size_t)b * 2048 + q0 + q) * 1024;
    out[ob + d0] = o0[r] * rv[r];
    out[ob + d0 + 32] = o1[r] * rv[r];
  }
}

extern "C" void kernel_launch(void* const* d_in, const int* in_sizes, int n_in,
                              void* d_out, int out_size, void* d_ws, size_t ws_size,
                              hipStream_t stream) {
  const float* x  = (const float*)d_in[0];
  const float* Wq = (const float*)d_in[1];
  const float* bq = (const float*)d_in[2];
  const float* Wk = (const float*)d_in[3];
  const float* bk = (const float*)d_in[4];
  const float* Wv = (const float*)d_in[5];
  const float* bv = (const float*)d_in[6];
  float* o = (float*)d_out;

  const size_t NX = (size_t)8192 * 1024;
  const size_t NW = (size_t)1024 * 1024;
  unsigned short* p = (unsigned short*)d_ws;
  unsigned short* Xth = p; p += NX;
  unsigned short* Xtl = p; p += NX;
  unsigned short* Qh = p; p += NX;
  unsigned short* Ql = p; p += NX;
  unsigned short* Kh = p; p += NX;
  unsigned short* Kl = p; p += NX;
  unsigned short* Vt = p; p += NX;
  unsigned short* Wqh = p; p += NW;
  unsigned short* Wql = p; p += NW;
  unsigned short* Wkh = p; p += NW;
  unsigned short* Wkl = p; p += NW;
  unsigned short* Wvh = p; p += NW;
  unsigned short* Wvl = p; p += NW;

  split_tiled_kernel<<<4096, 256, 0, stream>>>(x, Xth, Xtl, 16384);
  dim3 gs(512, 3);
  split3_kernel<<<gs, 256, 0, stream>>>(Wq, Wk, Wv, Wqh, Wql, Wkh, Wkl, Wvh, Wvl);

  dim3 gp(128, 2, 3), bp(512);
  proj_fused_kernel<<<gp, bp, 0, stream>>>(Xth, Xtl, Wqh, Wql, Wkh, Wkl, Wvh,
                                           bq, bk, bv, Qh, Ql, Kh, Kl, Vt);

  attn_kernel<<<256, 1024, 0, stream>>>(Qh, Ql, Kh, Kl, Vt, o);
}

// Round 7
// 226.152 us; speedup vs baseline: 5.9379x; 1.3354x over previous
//
#include <hip/hip_runtime.h>
#include <hip/hip_bf16.h>

// B=4, S=2048, H=1024. Inputs/outputs fp32.
// Proj: 3-pass split-bf16 (accurate fp32 result), outputs stored fp16.
// Attn: QK^T and PV in fp16 MFMA (32x32x16_f16); softmax fp32 exact.
// Layouts:
//   Xt/Wt bf16 hi/lo planes: [rows/16][k/32][512]; lane l's 8 elems at +l*8
//   Qf,Kf fp16: [b][s/32][h/16][srow 32][h 16]
//   Vt   fp16: [b][d/32][k/16][(d&31)*16 + (k&15)]
// ws (ushort): Xth Xtl Qf Kf Vt [8.39M each] + 6 W planes [1.05M] = ~97 MB

typedef __attribute__((ext_vector_type(4))) float f32x4;
typedef __attribute__((ext_vector_type(16))) float f32x16;
typedef __attribute__((ext_vector_type(8))) short bf16x8;
typedef __attribute__((ext_vector_type(8))) _Float16 f16x8;
typedef __attribute__((ext_vector_type(4))) unsigned short us4;
typedef __attribute__((ext_vector_type(8))) unsigned short us8;

#define MFMA16(a, b, c) __builtin_amdgcn_mfma_f32_16x16x32_bf16((a), (b), (c), 0, 0, 0)
#define MFMA32F(a, b, c) __builtin_amdgcn_mfma_f32_32x32x16_f16((a), (b), (c), 0, 0, 0)

static __device__ __forceinline__ unsigned short f2bf_u(float x) {
  __hip_bfloat16 h = __float2bfloat16(x);
  return *reinterpret_cast<unsigned short*>(&h);
}
static __device__ __forceinline__ float bfu2f(unsigned short u) {
  __hip_bfloat16 h;
  *reinterpret_cast<unsigned short*>(&h) = u;
  return __bfloat162float(h);
}
static __device__ __forceinline__ unsigned short f2h_u(float x) {
  _Float16 h = (_Float16)x;
  return *reinterpret_cast<unsigned short*>(&h);
}
static __device__ __forceinline__ void cvt8(f32x4 v0, f32x4 v1, bf16x8& h, bf16x8& l) {
#pragma unroll
  for (int j = 0; j < 4; j++) {
    unsigned short hu = f2bf_u(v0[j]);
    h[j] = (short)hu; l[j] = (short)f2bf_u(v0[j] - bfu2f(hu));
    hu = f2bf_u(v1[j]);
    h[j + 4] = (short)hu; l[j + 4] = (short)f2bf_u(v1[j] - bfu2f(hu));
  }
}

// fp32 [rows][1024] -> hi/lo bf16 fragment tiles [rows/16][32][512].
__global__ __launch_bounds__(256) void split_tiled_kernel(
    const float* __restrict__ in, unsigned short* __restrict__ hi,
    unsigned short* __restrict__ lo, int ntiles) {
  const int t = blockIdx.x * 256 + threadIdx.x;
  if (t >= ntiles * 64) return;
  const int tile = t >> 6;
  const int l = t & 63;
  const int mt = tile >> 5;
  const int kt = tile & 31;
  const int m = mt * 16 + (l & 15);
  const int kb = kt * 32 + (l >> 4) * 8;
  const float* src = in + (size_t)m * 1024 + kb;
  f32x4 v0 = *(const f32x4*)src;
  f32x4 v1 = *(const f32x4*)(src + 4);
  bf16x8 h, lv;
  cvt8(v0, v1, h, lv);
  *(bf16x8*)(hi + (size_t)tile * 512 + l * 8) = h;
  *(bf16x8*)(lo + (size_t)tile * 512 + l * 8) = lv;
}

// All three W splits in one dispatch.
__global__ __launch_bounds__(256) void split3_kernel(
    const float* __restrict__ w0, const float* __restrict__ w1,
    const float* __restrict__ w2,
    unsigned short* __restrict__ h0, unsigned short* __restrict__ l0,
    unsigned short* __restrict__ h1, unsigned short* __restrict__ l1,
    unsigned short* __restrict__ h2, unsigned short* __restrict__ l2) {
  const int which = blockIdx.y;
  const float* in = which == 0 ? w0 : (which == 1 ? w1 : w2);
  unsigned short* hi = which == 0 ? h0 : (which == 1 ? h1 : h2);
  unsigned short* lo = which == 0 ? l0 : (which == 1 ? l1 : l2);
  const int t = blockIdx.x * 256 + threadIdx.x;
  const int tile = t >> 6;
  const int l = t & 63;
  const int mt = tile >> 5;
  const int kt = tile & 31;
  const int m = mt * 16 + (l & 15);
  const int kb = kt * 32 + (l >> 4) * 8;
  const float* src = in + (size_t)m * 1024 + kb;
  f32x4 v0 = *(const f32x4*)src;
  f32x4 v1 = *(const f32x4*)(src + 4);
  bf16x8 h, lv;
  cvt8(v0, v1, h, lv);
  *(bf16x8*)(hi + (size_t)tile * 512 + l * 8) = h;
  *(bf16x8*)(lo + (size_t)tile * 512 + l * 8) = lv;
}

// Fused Q/K/V projection. Block: 64 m x 512 n; grid (128, 2, 3).
// z=0: Q (3-pass, fp16 store). z=1: K. z=2: V (1-pass, Vt fp16 store).
__global__ __launch_bounds__(512, 2) void proj_fused_kernel(
    const unsigned short* __restrict__ Xth, const unsigned short* __restrict__ Xtl,
    const unsigned short* __restrict__ Wqh, const unsigned short* __restrict__ Wql,
    const unsigned short* __restrict__ Wkh, const unsigned short* __restrict__ Wkl,
    const unsigned short* __restrict__ Wvh,
    const float* __restrict__ bq, const float* __restrict__ bk,
    const float* __restrict__ bv,
    unsigned short* __restrict__ Qf, unsigned short* __restrict__ Kf,
    unsigned short* __restrict__ Vt) {
  const int tid = threadIdx.x;
  const int lane = tid & 63;
  const int wid = tid >> 6;
  const int lrow = lane & 15;
  const int kg = lane >> 4;
  const int bx = blockIdx.x;               // 64-row m-block, 0..127
  const int ntb = blockIdx.y * 32 + wid * 4;
  const int z = blockIdx.z;

  const unsigned short* Wh = z == 0 ? Wqh : (z == 1 ? Wkh : Wvh);
  const unsigned short* Wl = z == 0 ? Wql : Wkl;
  const float* bias = z == 0 ? bq : (z == 1 ? bk : bv);

  const unsigned short* xh = Xth + (size_t)(bx * 4) * 32 * 512 + lane * 8;
  const unsigned short* xl = Xtl + (size_t)(bx * 4) * 32 * 512 + lane * 8;

  f32x4 acc[4][4];
#pragma unroll
  for (int mf = 0; mf < 4; mf++)
#pragma unroll
    for (int cf = 0; cf < 4; cf++) acc[mf][cf] = f32x4{0.f, 0.f, 0.f, 0.f};

  if (z < 2) {
    for (int kt = 0; kt < 32; kt++) {
      const size_t o = (size_t)kt * 512;
      bf16x8 ah[4], al[4];
#pragma unroll
      for (int mf = 0; mf < 4; mf++) {
        ah[mf] = *(const bf16x8*)(xh + (size_t)mf * 32 * 512 + o);
        al[mf] = *(const bf16x8*)(xl + (size_t)mf * 32 * 512 + o);
      }
#pragma unroll
      for (int cf = 0; cf < 4; cf++) {
        const size_t wo = ((size_t)(ntb + cf) * 32 + kt) * 512 + lane * 8;
        bf16x8 bh = *(const bf16x8*)(Wh + wo);
        bf16x8 bl = *(const bf16x8*)(Wl + wo);
#pragma unroll
        for (int mf = 0; mf < 4; mf++) {
          acc[mf][cf] = MFMA16(ah[mf], bh, acc[mf][cf]);
          acc[mf][cf] = MFMA16(ah[mf], bl, acc[mf][cf]);
          acc[mf][cf] = MFMA16(al[mf], bh, acc[mf][cf]);
        }
      }
    }
    unsigned short* O = z == 0 ? Qf : Kf;
    const int b = bx >> 5;
#pragma unroll
    for (int mf = 0; mf < 4; mf++) {
      const int st = (bx & 31) * 2 + (mf >> 1);
      const int srow0 = (mf & 1) * 16 + kg * 4;
#pragma unroll
      for (int cf = 0; cf < 4; cf++) {
        const int nt = ntb + cf;
        const float bv_ = bias[nt * 16 + lrow];
        const size_t base = ((size_t)((b * 64 + st) * 64 + nt)) * 512 + lrow;
#pragma unroll
        for (int i = 0; i < 4; i++) {
          O[base + (size_t)(srow0 + i) * 16] = f2h_u(acc[mf][cf][i] + bv_);
        }
      }
    }
  } else {
    for (int kt = 0; kt < 32; kt++) {
      const size_t o = (size_t)kt * 512;
      bf16x8 ah[4];
#pragma unroll
      for (int mf = 0; mf < 4; mf++)
        ah[mf] = *(const bf16x8*)(xh + (size_t)mf * 32 * 512 + o);
#pragma unroll
      for (int cf = 0; cf < 4; cf++) {
        const size_t wo = ((size_t)(ntb + cf) * 32 + kt) * 512 + lane * 8;
        bf16x8 bh = *(const bf16x8*)(Wh + wo);
#pragma unroll
        for (int mf = 0; mf < 4; mf++) acc[mf][cf] = MFMA16(ah[mf], bh, acc[mf][cf]);
      }
    }
    const int b = bx >> 5;
#pragma unroll
    for (int mf = 0; mf < 4; mf++) {
      const int kl_hi = (bx & 31) * 4 + mf;
#pragma unroll
      for (int cf = 0; cf < 4; cf++) {
        const int d = (ntb + cf) * 16 + lrow;
        const float bv_ = bias[d];
        us4 pk;
#pragma unroll
        for (int i = 0; i < 4; i++) pk[i] = f2h_u(acc[mf][cf][i] + bv_);
        const size_t a = ((size_t)(b * 32 + (d >> 5)) * 128 + kl_hi) * 512 +
                         (size_t)(d & 31) * 16 + kg * 4;
        *reinterpret_cast<us4*>(&Vt[a]) = pk;
      }
    }
  }
}

// attn: one block per (batch, 32 q-rows); 16 waves / 1024 threads.
// Q staged in LDS (64 KB, later reused as P buffer). K/V register
// double-buffered prefetch. fp16 MFMA 32x32x16.
__global__ __launch_bounds__(1024, 4) void attn_kernel(
    const unsigned short* __restrict__ Qf, const unsigned short* __restrict__ Kf,
    const unsigned short* __restrict__ Vt, float* __restrict__ out) {
  __shared__ unsigned short LDSB[65536];  // Q (first 32768) then P (all)
  __shared__ float redM[16][32];
  __shared__ float redS[16][32];
  __shared__ float rowinv[32];

  const int tid = threadIdx.x;
  const int lane = tid & 63;
  const int wid = tid >> 6;  // 0..15
  const int lq = lane & 31;
  const int hi = lane >> 5;
  const int lo16 = lq * 16 + hi * 8;

  const int id = blockIdx.x;
  const int xcd = id & 7;
  const int b = xcd >> 1;
  const int qt = (xcd & 1) + ((id >> 3) << 1);  // 0..63
  const int q0 = qt * 32;

  // ---- Stage Q tile (64 KB) into LDS ----
  {
    const unsigned short* qsrc = Qf + ((size_t)(b * 64 + qt) * 64) * 512;
#pragma unroll
    for (int i = 0; i < 4; i++) {
      const int idx = (i * 1024 + tid) * 8;
      *(us8*)&LDSB[idx] = *(const us8*)&qsrc[idx];
    }
  }
  __syncthreads();

  // ---- QK^T: fp16, K prefetched (reg double-buffer) ----
  f32x16 acc0, acc1, acc2, acc3;
#pragma unroll
  for (int r = 0; r < 16; r++) { acc0[r] = 0.f; acc1[r] = 0.f; acc2[r] = 0.f; acc3[r] = 0.f; }

  const unsigned short* kb = Kf + ((size_t)(b * 64 + wid * 4) * 64) * 512 + lo16;
#define KLD(G, KKK) (*(const f16x8*)(kb + (size_t)(G)*64 * 512 + (size_t)(KKK)*512))
  f16x8 kc0 = KLD(0, 0), kc1 = KLD(1, 0), kc2 = KLD(2, 0), kc3 = KLD(3, 0);
  for (int kk = 0; kk < 63; kk++) {
    f16x8 q = *(const f16x8*)&LDSB[kk * 512 + lo16];
    f16x8 kn0 = KLD(0, kk + 1), kn1 = KLD(1, kk + 1),
          kn2 = KLD(2, kk + 1), kn3 = KLD(3, kk + 1);
    __builtin_amdgcn_s_setprio(1);
    acc0 = MFMA32F(kc0, q, acc0);
    acc1 = MFMA32F(kc1, q, acc1);
    acc2 = MFMA32F(kc2, q, acc2);
    acc3 = MFMA32F(kc3, q, acc3);
    __builtin_amdgcn_s_setprio(0);
    kc0 = kn0; kc1 = kn1; kc2 = kn2; kc3 = kn3;
  }
  {
    f16x8 q = *(const f16x8*)&LDSB[63 * 512 + lo16];
    acc0 = MFMA32F(kc0, q, acc0);
    acc1 = MFMA32F(kc1, q, acc1);
    acc2 = MFMA32F(kc2, q, acc2);
    acc3 = MFMA32F(kc3, q, acc3);
  }
#undef KLD

  // ---- softmax (exact) ----
  float m = -3.0e38f;
#pragma unroll
  for (int r = 0; r < 16; r++) {
    m = fmaxf(m, fmaxf(fmaxf(acc0[r], acc1[r]), fmaxf(acc2[r], acc3[r])));
  }
  m = fmaxf(m, __shfl_xor(m, 32));
  if (hi == 0) redM[wid][lq] = m;
  __syncthreads();
  float M = redM[0][lq];
#pragma unroll
  for (int w = 1; w < 16; w++) M = fmaxf(M, redM[w][lq]);

  float s = 0.f;
#pragma unroll
  for (int r = 0; r < 16; r++) {
    acc0[r] = __expf(acc0[r] - M); s += acc0[r];
    acc1[r] = __expf(acc1[r] - M); s += acc1[r];
    acc2[r] = __expf(acc2[r] - M); s += acc2[r];
    acc3[r] = __expf(acc3[r] - M); s += acc3[r];
  }
  s += __shfl_xor(s, 32);
  if (hi == 0) redS[wid][lq] = s;
  __syncthreads();
  if (tid < 32) {
    float ss = 0.f;
#pragma unroll
    for (int w = 0; w < 16; w++) ss += redS[w][tid];
    rowinv[tid] = 1.0f / ss;
  }

  // ---- P -> fp16 LDS (XOR swizzle); overwrites Q region (safe: all waves
  // passed the softmax barriers above) ----
  const int swz = (lq & 7) << 3;
  const int pb = lq * 2048 + wid * 128 + 4 * hi;
#define PWRITE(GG, ACC)                                                     \
  {                                                                         \
    _Pragma("unroll")                                                       \
    for (int qd = 0; qd < 4; qd++) {                                        \
      us4 pk;                                                               \
      _Pragma("unroll")                                                     \
      for (int i = 0; i < 4; i++) pk[i] = f2h_u(ACC[qd * 4 + i]);           \
      *(us4*)&LDSB[(pb + (GG)*32 + qd * 8) ^ swz] = pk;                     \
    }                                                                       \
  }
  PWRITE(0, acc0)
  PWRITE(1, acc1)
  PWRITE(2, acc2)
  PWRITE(3, acc3)
#undef PWRITE
  __syncthreads();

  // ---- O = P @ V, V prefetched ----
  f32x16 o0, o1;
#pragma unroll
  for (int r = 0; r < 16; r++) { o0[r] = 0.f; o1[r] = 0.f; }

  const unsigned short* vt0 = Vt + ((size_t)(b * 32 + wid * 2) * 128) * 512 + lo16;
  const unsigned short* vt1 = vt0 + (size_t)128 * 512;
  const int prow = lq * 2048 + hi * 8;
#define VLD(P, KKK) (*(const f16x8*)((P) + (size_t)(KKK)*512))
  f16x8 vc0 = VLD(vt0, 0), vc1 = VLD(vt1, 0);
  for (int kk = 0; kk < 127; kk++) {
    f16x8 pa = *(const f16x8*)&LDSB[(prow + kk * 16) ^ swz];
    f16x8 vn0 = VLD(vt0, kk + 1), vn1 = VLD(vt1, kk + 1);
    __builtin_amdgcn_s_setprio(1);
    o0 = MFMA32F(pa, vc0, o0);
    o1 = MFMA32F(pa, vc1, o1);
    __builtin_amdgcn_s_setprio(0);
    vc0 = vn0; vc1 = vn1;
  }
  {
    f16x8 pa = *(const f16x8*)&LDSB[(prow + 127 * 16) ^ swz];
    o0 = MFMA32F(pa, vc0, o0);
    o1 = MFMA32F(pa, vc1, o1);
  }
#undef VLD

  // ---- Epilogue ----
  float rv[16];
#pragma unroll
  for (int r = 0; r < 16; r++) rv[r] = rowinv[(r & 3) + 8 * (r >> 2) + 4 * hi];
  const int d0 = wid * 64 + lq;
#pragma unroll
  for (int r = 0; r < 16; r++) {
    const int q = (r & 3) + 8 * (r >> 2) + 4 * hi;
    const size_t ob = ((size_t)b * 2048 + q0 + q) * 1024;
    out[ob + d0] = o0[r] * rv[r];
    out[ob + d0 + 32] = o1[r] * rv[r];
  }
}

extern "C" void kernel_launch(void* const* d_in, const int* in_sizes, int n_in,
                              void* d_out, int out_size, void* d_ws, size_t ws_size,
                              hipStream_t stream) {
  const float* x  = (const float*)d_in[0];
  const float* Wq = (const float*)d_in[1];
  const float* bq = (const float*)d_in[2];
  const float* Wk = (const float*)d_in[3];
  const float* bk = (const float*)d_in[4];
  const float* Wv = (const float*)d_in[5];
  const float* bv = (const float*)d_in[6];
  float* o = (float*)d_out;

  const size_t NX = (size_t)8192 * 1024;
  const size_t NW = (size_t)1024 * 1024;
  unsigned short* p = (unsigned short*)d_ws;
  unsigned short* Xth = p; p += NX;
  unsigned short* Xtl = p; p += NX;
  unsigned short* Qf = p; p += NX;
  unsigned short* Kf = p; p += NX;
  unsigned short* Vt = p; p += NX;
  unsigned short* Wqh = p; p += NW;
  unsigned short* Wql = p; p += NW;
  unsigned short* Wkh = p; p += NW;
  unsigned short* Wkl = p; p += NW;
  unsigned short* Wvh = p; p += NW;
  unsigned short* Wvl = p; p += NW;

  split_tiled_kernel<<<4096, 256, 0, stream>>>(x, Xth, Xtl, 16384);
  dim3 gs(512, 3);
  split3_kernel<<<gs, 256, 0, stream>>>(Wq, Wk, Wv, Wqh, Wql, Wkh, Wkl, Wvh, Wvl);

  dim3 gp(128, 2, 3), bp(512);
  proj_fused_kernel<<<gp, bp, 0, stream>>>(Xth, Xtl, Wqh, Wql, Wkh, Wkl, Wvh,
                                           bq, bk, bv, Qf, Kf, Vt);

  attn_kernel<<<256, 1024, 0, stream>>>(Qf, Kf, Vt, o);
}

// Round 8
// 207.743 us; speedup vs baseline: 6.4640x; 1.0886x over previous
//
#include <hip/hip_runtime.h>
#include <hip/hip_bf16.h>

// B=4, S=2048, H=1024. Inputs/outputs fp32.
// Proj: 2-pass fp16 (X fp16 1-plane; W fp16 hi+lo planes), fp32 accum.
// Attn: QK^T and PV in fp16 MFMA (32x32x16_f16); softmax fp32 exact.
// Layouts (all fragment-native):
//   Xf / W planes: [rows/16][k/32][512] fp16; lane l's 8 elems at +l*8
//   Qf,Kf fp16: [b][s/32][h/16][srow 32][h 16]
//   Vt   fp16: [b][d/32][k/16][(d&31)*16 + (k&15)]
// ws (ushort): Xf Qf Kf Vt [8.39M each] + 5 W planes [1.05M] = ~78 MB

typedef __attribute__((ext_vector_type(4))) float f32x4;
typedef __attribute__((ext_vector_type(16))) float f32x16;
typedef __attribute__((ext_vector_type(8))) _Float16 f16x8;
typedef __attribute__((ext_vector_type(4))) unsigned short us4;
typedef __attribute__((ext_vector_type(8))) unsigned short us8;

#define MFMA16F(a, b, c) __builtin_amdgcn_mfma_f32_16x16x32_f16((a), (b), (c), 0, 0, 0)
#define MFMA32F(a, b, c) __builtin_amdgcn_mfma_f32_32x32x16_f16((a), (b), (c), 0, 0, 0)

static __device__ __forceinline__ unsigned short f2h_u(float x) {
  _Float16 h = (_Float16)x;
  return *reinterpret_cast<unsigned short*>(&h);
}
static __device__ __forceinline__ float hu2f(unsigned short u) {
  _Float16 h;
  *reinterpret_cast<unsigned short*>(&h) = u;
  return (float)h;
}

// fp32 [rows][1024] -> fp16 fragment tiles [rows/16][32][512] (single plane).
__global__ __launch_bounds__(256) void split_x_kernel(
    const float* __restrict__ in, unsigned short* __restrict__ outp, int ntiles) {
  const int t = blockIdx.x * 256 + threadIdx.x;
  if (t >= ntiles * 64) return;
  const int tile = t >> 6;
  const int l = t & 63;
  const int m = (tile >> 5) * 16 + (l & 15);
  const int kb = (tile & 31) * 32 + (l >> 4) * 8;
  const float* src = in + (size_t)m * 1024 + kb;
  f32x4 v0 = *(const f32x4*)src;
  f32x4 v1 = *(const f32x4*)(src + 4);
  us8 h;
#pragma unroll
  for (int j = 0; j < 4; j++) {
    h[j] = f2h_u(v0[j]);
    h[j + 4] = f2h_u(v1[j]);
  }
  *(us8*)(outp + (size_t)tile * 512 + l * 8) = h;
}

// All three W splits (fp16 hi/lo) in one dispatch; blockIdx.y selects matrix.
// For z==2 (V) only the hi plane is consumed later; lo still written (cheap).
__global__ __launch_bounds__(256) void split3_kernel(
    const float* __restrict__ w0, const float* __restrict__ w1,
    const float* __restrict__ w2,
    unsigned short* __restrict__ h0, unsigned short* __restrict__ l0,
    unsigned short* __restrict__ h1, unsigned short* __restrict__ l1,
    unsigned short* __restrict__ h2, unsigned short* __restrict__ l2) {
  const int which = blockIdx.y;
  const float* in = which == 0 ? w0 : (which == 1 ? w1 : w2);
  unsigned short* hi = which == 0 ? h0 : (which == 1 ? h1 : h2);
  unsigned short* lo = which == 0 ? l0 : (which == 1 ? l1 : l2);
  const int t = blockIdx.x * 256 + threadIdx.x;
  const int tile = t >> 6;
  const int l = t & 63;
  const int m = (tile >> 5) * 16 + (l & 15);
  const int kb = (tile & 31) * 32 + (l >> 4) * 8;
  const float* src = in + (size_t)m * 1024 + kb;
  f32x4 v0 = *(const f32x4*)src;
  f32x4 v1 = *(const f32x4*)(src + 4);
  us8 h, lv;
#pragma unroll
  for (int j = 0; j < 4; j++) {
    unsigned short hu = f2h_u(v0[j]);
    h[j] = hu;
    lv[j] = f2h_u(v0[j] - hu2f(hu));
    hu = f2h_u(v1[j]);
    h[j + 4] = hu;
    lv[j + 4] = f2h_u(v1[j] - hu2f(hu));
  }
  *(us8*)(hi + (size_t)tile * 512 + l * 8) = h;
  *(us8*)(lo + (size_t)tile * 512 + l * 8) = lv;
}

// Fused Q/K/V projection. Block: 64 m x 512 n; grid (128, 2, 3).
// z=0: Q (2-pass fp16). z=1: K. z=2: V (1-pass, Vt store).
__global__ __launch_bounds__(512, 2) void proj_fused_kernel(
    const unsigned short* __restrict__ Xf,
    const unsigned short* __restrict__ Wqh, const unsigned short* __restrict__ Wql,
    const unsigned short* __restrict__ Wkh, const unsigned short* __restrict__ Wkl,
    const unsigned short* __restrict__ Wvh,
    const float* __restrict__ bq, const float* __restrict__ bk,
    const float* __restrict__ bv,
    unsigned short* __restrict__ Qf, unsigned short* __restrict__ Kf,
    unsigned short* __restrict__ Vt) {
  const int tid = threadIdx.x;
  const int lane = tid & 63;
  const int wid = tid >> 6;
  const int lrow = lane & 15;
  const int kg = lane >> 4;
  const int bx = blockIdx.x;               // 64-row m-block, 0..127
  const int ntb = blockIdx.y * 32 + wid * 4;
  const int z = blockIdx.z;

  const unsigned short* Wh = z == 0 ? Wqh : (z == 1 ? Wkh : Wvh);
  const unsigned short* Wl = z == 0 ? Wql : Wkl;
  const float* bias = z == 0 ? bq : (z == 1 ? bk : bv);

  const unsigned short* xf = Xf + (size_t)(bx * 4) * 32 * 512 + lane * 8;

  f32x4 acc[4][4];
#pragma unroll
  for (int mf = 0; mf < 4; mf++)
#pragma unroll
    for (int cf = 0; cf < 4; cf++) acc[mf][cf] = f32x4{0.f, 0.f, 0.f, 0.f};

  if (z < 2) {
    for (int kt = 0; kt < 32; kt++) {
      const size_t o = (size_t)kt * 512;
      f16x8 ah[4];
#pragma unroll
      for (int mf = 0; mf < 4; mf++)
        ah[mf] = *(const f16x8*)(xf + (size_t)mf * 32 * 512 + o);
#pragma unroll
      for (int cf = 0; cf < 4; cf++) {
        const size_t wo = ((size_t)(ntb + cf) * 32 + kt) * 512 + lane * 8;
        f16x8 bh = *(const f16x8*)(Wh + wo);
        f16x8 bl = *(const f16x8*)(Wl + wo);
#pragma unroll
        for (int mf = 0; mf < 4; mf++) {
          acc[mf][cf] = MFMA16F(ah[mf], bh, acc[mf][cf]);
          acc[mf][cf] = MFMA16F(ah[mf], bl, acc[mf][cf]);
        }
      }
    }
    unsigned short* O = z == 0 ? Qf : Kf;
    const int b = bx >> 5;
#pragma unroll
    for (int mf = 0; mf < 4; mf++) {
      const int st = (bx & 31) * 2 + (mf >> 1);
      const int srow0 = (mf & 1) * 16 + kg * 4;
#pragma unroll
      for (int cf = 0; cf < 4; cf++) {
        const int nt = ntb + cf;
        const float bv_ = bias[nt * 16 + lrow];
        const size_t base = ((size_t)((b * 64 + st) * 64 + nt)) * 512 + lrow;
#pragma unroll
        for (int i = 0; i < 4; i++) {
          O[base + (size_t)(srow0 + i) * 16] = f2h_u(acc[mf][cf][i] + bv_);
        }
      }
    }
  } else {
    for (int kt = 0; kt < 32; kt++) {
      const size_t o = (size_t)kt * 512;
      f16x8 ah[4];
#pragma unroll
      for (int mf = 0; mf < 4; mf++)
        ah[mf] = *(const f16x8*)(xf + (size_t)mf * 32 * 512 + o);
#pragma unroll
      for (int cf = 0; cf < 4; cf++) {
        const size_t wo = ((size_t)(ntb + cf) * 32 + kt) * 512 + lane * 8;
        f16x8 bh = *(const f16x8*)(Wh + wo);
#pragma unroll
        for (int mf = 0; mf < 4; mf++) acc[mf][cf] = MFMA16F(ah[mf], bh, acc[mf][cf]);
      }
    }
    const int b = bx >> 5;
#pragma unroll
    for (int mf = 0; mf < 4; mf++) {
      const int kl_hi = (bx & 31) * 4 + mf;
#pragma unroll
      for (int cf = 0; cf < 4; cf++) {
        const int d = (ntb + cf) * 16 + lrow;
        const float bv_ = bias[d];
        us4 pk;
#pragma unroll
        for (int i = 0; i < 4; i++) pk[i] = f2h_u(acc[mf][cf][i] + bv_);
        const size_t a = ((size_t)(b * 32 + (d >> 5)) * 128 + kl_hi) * 512 +
                         (size_t)(d & 31) * 16 + kg * 4;
        *reinterpret_cast<us4*>(&Vt[a]) = pk;
      }
    }
  }
}

// attn: one block per (batch, 32 q-rows); 16 waves / 1024 threads.
// Q staged in LDS (64 KB, later reused as P buffer). K/V register
// double-buffered prefetch. fp16 MFMA 32x32x16. (unchanged from R7)
__global__ __launch_bounds__(1024, 4) void attn_kernel(
    const unsigned short* __restrict__ Qf, const unsigned short* __restrict__ Kf,
    const unsigned short* __restrict__ Vt, float* __restrict__ out) {
  __shared__ unsigned short LDSB[65536];  // Q (first 32768) then P (all)
  __shared__ float redM[16][32];
  __shared__ float redS[16][32];
  __shared__ float rowinv[32];

  const int tid = threadIdx.x;
  const int lane = tid & 63;
  const int wid = tid >> 6;  // 0..15
  const int lq = lane & 31;
  const int hi = lane >> 5;
  const int lo16 = lq * 16 + hi * 8;

  const int id = blockIdx.x;
  const int xcd = id & 7;
  const int b = xcd >> 1;
  const int qt = (xcd & 1) + ((id >> 3) << 1);  // 0..63
  const int q0 = qt * 32;

  // ---- Stage Q tile (64 KB) into LDS ----
  {
    const unsigned short* qsrc = Qf + ((size_t)(b * 64 + qt) * 64) * 512;
#pragma unroll
    for (int i = 0; i < 4; i++) {
      const int idx = (i * 1024 + tid) * 8;
      *(us8*)&LDSB[idx] = *(const us8*)&qsrc[idx];
    }
  }
  __syncthreads();

  // ---- QK^T: fp16, K prefetched (reg double-buffer) ----
  f32x16 acc0, acc1, acc2, acc3;
#pragma unroll
  for (int r = 0; r < 16; r++) { acc0[r] = 0.f; acc1[r] = 0.f; acc2[r] = 0.f; acc3[r] = 0.f; }

  const unsigned short* kb = Kf + ((size_t)(b * 64 + wid * 4) * 64) * 512 + lo16;
#define KLD(G, KKK) (*(const f16x8*)(kb + (size_t)(G)*64 * 512 + (size_t)(KKK)*512))
  f16x8 kc0 = KLD(0, 0), kc1 = KLD(1, 0), kc2 = KLD(2, 0), kc3 = KLD(3, 0);
  for (int kk = 0; kk < 63; kk++) {
    f16x8 q = *(const f16x8*)&LDSB[kk * 512 + lo16];
    f16x8 kn0 = KLD(0, kk + 1), kn1 = KLD(1, kk + 1),
          kn2 = KLD(2, kk + 1), kn3 = KLD(3, kk + 1);
    __builtin_amdgcn_s_setprio(1);
    acc0 = MFMA32F(kc0, q, acc0);
    acc1 = MFMA32F(kc1, q, acc1);
    acc2 = MFMA32F(kc2, q, acc2);
    acc3 = MFMA32F(kc3, q, acc3);
    __builtin_amdgcn_s_setprio(0);
    kc0 = kn0; kc1 = kn1; kc2 = kn2; kc3 = kn3;
  }
  {
    f16x8 q = *(const f16x8*)&LDSB[63 * 512 + lo16];
    acc0 = MFMA32F(kc0, q, acc0);
    acc1 = MFMA32F(kc1, q, acc1);
    acc2 = MFMA32F(kc2, q, acc2);
    acc3 = MFMA32F(kc3, q, acc3);
  }
#undef KLD

  // ---- softmax (exact) ----
  float m = -3.0e38f;
#pragma unroll
  for (int r = 0; r < 16; r++) {
    m = fmaxf(m, fmaxf(fmaxf(acc0[r], acc1[r]), fmaxf(acc2[r], acc3[r])));
  }
  m = fmaxf(m, __shfl_xor(m, 32));
  if (hi == 0) redM[wid][lq] = m;
  __syncthreads();
  float M = redM[0][lq];
#pragma unroll
  for (int w = 1; w < 16; w++) M = fmaxf(M, redM[w][lq]);

  float s = 0.f;
#pragma unroll
  for (int r = 0; r < 16; r++) {
    acc0[r] = __expf(acc0[r] - M); s += acc0[r];
    acc1[r] = __expf(acc1[r] - M); s += acc1[r];
    acc2[r] = __expf(acc2[r] - M); s += acc2[r];
    acc3[r] = __expf(acc3[r] - M); s += acc3[r];
  }
  s += __shfl_xor(s, 32);
  if (hi == 0) redS[wid][lq] = s;
  __syncthreads();
  if (tid < 32) {
    float ss = 0.f;
#pragma unroll
    for (int w = 0; w < 16; w++) ss += redS[w][tid];
    rowinv[tid] = 1.0f / ss;
  }

  // ---- P -> fp16 LDS (XOR swizzle); overwrites Q region ----
  const int swz = (lq & 7) << 3;
  const int pb = lq * 2048 + wid * 128 + 4 * hi;
#define PWRITE(GG, ACC)                                                     \
  {                                                                         \
    _Pragma("unroll")                                                       \
    for (int qd = 0; qd < 4; qd++) {                                        \
      us4 pk;                                                               \
      _Pragma("unroll")                                                     \
      for (int i = 0; i < 4; i++) pk[i] = f2h_u(ACC[qd * 4 + i]);           \
      *(us4*)&LDSB[(pb + (GG)*32 + qd * 8) ^ swz] = pk;                     \
    }                                                                       \
  }
  PWRITE(0, acc0)
  PWRITE(1, acc1)
  PWRITE(2, acc2)
  PWRITE(3, acc3)
#undef PWRITE
  __syncthreads();

  // ---- O = P @ V, V prefetched ----
  f32x16 o0, o1;
#pragma unroll
  for (int r = 0; r < 16; r++) { o0[r] = 0.f; o1[r] = 0.f; }

  const unsigned short* vt0 = Vt + ((size_t)(b * 32 + wid * 2) * 128) * 512 + lo16;
  const unsigned short* vt1 = vt0 + (size_t)128 * 512;
  const int prow = lq * 2048 + hi * 8;
#define VLD(P, KKK) (*(const f16x8*)((P) + (size_t)(KKK)*512))
  f16x8 vc0 = VLD(vt0, 0), vc1 = VLD(vt1, 0);
  for (int kk = 0; kk < 127; kk++) {
    f16x8 pa = *(const f16x8*)&LDSB[(prow + kk * 16) ^ swz];
    f16x8 vn0 = VLD(vt0, kk + 1), vn1 = VLD(vt1, kk + 1);
    __builtin_amdgcn_s_setprio(1);
    o0 = MFMA32F(pa, vc0, o0);
    o1 = MFMA32F(pa, vc1, o1);
    __builtin_amdgcn_s_setprio(0);
    vc0 = vn0; vc1 = vn1;
  }
  {
    f16x8 pa = *(const f16x8*)&LDSB[(prow + 127 * 16) ^ swz];
    o0 = MFMA32F(pa, vc0, o0);
    o1 = MFMA32F(pa, vc1, o1);
  }
#undef VLD

  // ---- Epilogue ----
  float rv[16];
#pragma unroll
  for (int r = 0; r < 16; r++) rv[r] = rowinv[(r & 3) + 8 * (r >> 2) + 4 * hi];
  const int d0 = wid * 64 + lq;
#pragma unroll
  for (int r = 0; r < 16; r++) {
    const int q = (r & 3) + 8 * (r >> 2) + 4 * hi;
    const size_t ob = ((size_t)b * 2048 + q0 + q) * 1024;
    out[ob + d0] = o0[r] * rv[r];
    out[ob + d0 + 32] = o1[r] * rv[r];
  }
}

extern "C" void kernel_launch(void* const* d_in, const int* in_sizes, int n_in,
                              void* d_out, int out_size, void* d_ws, size_t ws_size,
                              hipStream_t stream) {
  const float* x  = (const float*)d_in[0];
  const float* Wq = (const float*)d_in[1];
  const float* bq = (const float*)d_in[2];
  const float* Wk = (const float*)d_in[3];
  const float* bk = (const float*)d_in[4];
  const float* Wv = (const float*)d_in[5];
  const float* bv = (const float*)d_in[6];
  float* o = (float*)d_out;

  const size_t NX = (size_t)8192 * 1024;
  const size_t NW = (size_t)1024 * 1024;
  unsigned short* p = (unsigned short*)d_ws;
  unsigned short* Xf = p; p += NX;
  unsigned short* Qf = p; p += NX;
  unsigned short* Kf = p; p += NX;
  unsigned short* Vt = p; p += NX;
  unsigned short* Wqh = p; p += NW;
  unsigned short* Wql = p; p += NW;
  unsigned short* Wkh = p; p += NW;
  unsigned short* Wkl = p; p += NW;
  unsigned short* Wvh = p; p += NW;
  unsigned short* Wvl = p; p += NW;

  split_x_kernel<<<4096, 256, 0, stream>>>(x, Xf, 16384);
  dim3 gs(512, 3);
  split3_kernel<<<gs, 256, 0, stream>>>(Wq, Wk, Wv, Wqh, Wql, Wkh, Wkl, Wvh, Wvl);

  dim3 gp(128, 2, 3), bp(512);
  proj_fused_kernel<<<gp, bp, 0, stream>>>(Xf, Wqh, Wql, Wkh, Wkl, Wvh,
                                           bq, bk, bv, Qf, Kf, Vt);

  attn_kernel<<<256, 1024, 0, stream>>>(Qf, Kf, Vt, o);
}

// Round 9
// 187.414 us; speedup vs baseline: 7.1652x; 1.1085x over previous
//
#include <hip/hip_runtime.h>
#include <hip/hip_bf16.h>

// B=4, S=2048, H=1024. Inputs/outputs fp32.
// Proj: 2-pass fp16 (X fp16 1-plane; W fp16 hi+lo planes), fp32 accum.
// Attn: QK^T and PV in fp16 MFMA (32x32x16_f16); softmax fp32 exact.
// Layouts (all fragment-native):
//   Xf / W planes: [rows/16][k/32][512] fp16; lane l's 8 elems at +l*8
//   Qf,Kf fp16: [b][s/32][h/16][srow 32][h 16]
//   Vt   fp16: [b][d/32][k/16][(d&31)*16 + (k&15)]
// ws (ushort): Xf Qf Kf Vt [8.39M each] + 5 W planes [1.05M] = ~78 MB

typedef __attribute__((ext_vector_type(4))) float f32x4;
typedef __attribute__((ext_vector_type(16))) float f32x16;
typedef __attribute__((ext_vector_type(8))) _Float16 f16x8;
typedef __attribute__((ext_vector_type(4))) unsigned short us4;
typedef __attribute__((ext_vector_type(8))) unsigned short us8;

#define MFMA16F(a, b, c) __builtin_amdgcn_mfma_f32_16x16x32_f16((a), (b), (c), 0, 0, 0)
#define MFMA32F(a, b, c) __builtin_amdgcn_mfma_f32_32x32x16_f16((a), (b), (c), 0, 0, 0)

static __device__ __forceinline__ unsigned short f2h_u(float x) {
  _Float16 h = (_Float16)x;
  return *reinterpret_cast<unsigned short*>(&h);
}
static __device__ __forceinline__ float hu2f(unsigned short u) {
  _Float16 h;
  *reinterpret_cast<unsigned short*>(&h) = u;
  return (float)h;
}

// fp32 [rows][1024] -> fp16 fragment tiles [rows/16][32][512] (single plane).
__global__ __launch_bounds__(256) void split_x_kernel(
    const float* __restrict__ in, unsigned short* __restrict__ outp, int ntiles) {
  const int t = blockIdx.x * 256 + threadIdx.x;
  if (t >= ntiles * 64) return;
  const int tile = t >> 6;
  const int l = t & 63;
  const int m = (tile >> 5) * 16 + (l & 15);
  const int kb = (tile & 31) * 32 + (l >> 4) * 8;
  const float* src = in + (size_t)m * 1024 + kb;
  f32x4 v0 = *(const f32x4*)src;
  f32x4 v1 = *(const f32x4*)(src + 4);
  us8 h;
#pragma unroll
  for (int j = 0; j < 4; j++) {
    h[j] = f2h_u(v0[j]);
    h[j + 4] = f2h_u(v1[j]);
  }
  *(us8*)(outp + (size_t)tile * 512 + l * 8) = h;
}

// All three W splits (fp16 hi/lo) in one dispatch; blockIdx.y selects matrix.
// which==2 (V): only hi plane consumed later; lo store skipped.
__global__ __launch_bounds__(256) void split3_kernel(
    const float* __restrict__ w0, const float* __restrict__ w1,
    const float* __restrict__ w2,
    unsigned short* __restrict__ h0, unsigned short* __restrict__ l0,
    unsigned short* __restrict__ h1, unsigned short* __restrict__ l1,
    unsigned short* __restrict__ h2, unsigned short* __restrict__ l2) {
  const int which = blockIdx.y;
  const float* in = which == 0 ? w0 : (which == 1 ? w1 : w2);
  unsigned short* hi = which == 0 ? h0 : (which == 1 ? h1 : h2);
  unsigned short* lo = which == 0 ? l0 : (which == 1 ? l1 : l2);
  const int t = blockIdx.x * 256 + threadIdx.x;
  const int tile = t >> 6;
  const int l = t & 63;
  const int m = (tile >> 5) * 16 + (l & 15);
  const int kb = (tile & 31) * 32 + (l >> 4) * 8;
  const float* src = in + (size_t)m * 1024 + kb;
  f32x4 v0 = *(const f32x4*)src;
  f32x4 v1 = *(const f32x4*)(src + 4);
  us8 h, lv;
#pragma unroll
  for (int j = 0; j < 4; j++) {
    unsigned short hu = f2h_u(v0[j]);
    h[j] = hu;
    lv[j] = f2h_u(v0[j] - hu2f(hu));
    hu = f2h_u(v1[j]);
    h[j + 4] = hu;
    lv[j + 4] = f2h_u(v1[j] - hu2f(hu));
  }
  *(us8*)(hi + (size_t)tile * 512 + l * 8) = h;
  if (which != 2) *(us8*)(lo + (size_t)tile * 512 + l * 8) = lv;
}

// Fused Q/K/V projection. Block: 128 m x 256 n, 4 waves (8mf x 4cf reg tile).
// grid (64, 4, 3); z slowest (W L2-residency per matrix phase).
// z=0: Q (2-pass fp16). z=1: K. z=2: V (1-pass, Vt store).
__global__ __launch_bounds__(256, 2) void proj_fused_kernel(
    const unsigned short* __restrict__ Xf,
    const unsigned short* __restrict__ Wqh, const unsigned short* __restrict__ Wql,
    const unsigned short* __restrict__ Wkh, const unsigned short* __restrict__ Wkl,
    const unsigned short* __restrict__ Wvh,
    const float* __restrict__ bq, const float* __restrict__ bk,
    const float* __restrict__ bv,
    unsigned short* __restrict__ Qf, unsigned short* __restrict__ Kf,
    unsigned short* __restrict__ Vt) {
  const int tid = threadIdx.x;
  const int lane = tid & 63;
  const int wid = tid >> 6;   // 0..3
  const int lrow = lane & 15;
  const int kg = lane >> 4;
  const int bx = blockIdx.x;               // 128-row m-block, 0..63
  const int ntb = blockIdx.y * 16 + wid * 4;  // n-tile base (16 cols each)
  const int z = blockIdx.z;

  const unsigned short* Wh = z == 0 ? Wqh : (z == 1 ? Wkh : Wvh);
  const unsigned short* Wl = z == 0 ? Wql : Wkl;
  const float* bias = z == 0 ? bq : (z == 1 ? bk : bv);

  const unsigned short* xf = Xf + (size_t)(bx * 8) * 32 * 512 + lane * 8;

  f32x4 acc[8][4];
#pragma unroll
  for (int mf = 0; mf < 8; mf++)
#pragma unroll
    for (int cf = 0; cf < 4; cf++) acc[mf][cf] = f32x4{0.f, 0.f, 0.f, 0.f};

  if (z < 2) {
    for (int kt = 0; kt < 32; kt++) {
      const size_t o = (size_t)kt * 512;
      f16x8 ah[8];
#pragma unroll
      for (int mf = 0; mf < 8; mf++)
        ah[mf] = *(const f16x8*)(xf + (size_t)mf * 32 * 512 + o);
#pragma unroll
      for (int cf = 0; cf < 4; cf++) {
        const size_t wo = ((size_t)(ntb + cf) * 32 + kt) * 512 + lane * 8;
        f16x8 bh = *(const f16x8*)(Wh + wo);
        f16x8 bl = *(const f16x8*)(Wl + wo);
#pragma unroll
        for (int mf = 0; mf < 8; mf++) {
          acc[mf][cf] = MFMA16F(ah[mf], bh, acc[mf][cf]);
          acc[mf][cf] = MFMA16F(ah[mf], bl, acc[mf][cf]);
        }
      }
    }
    unsigned short* O = z == 0 ? Qf : Kf;
    const int b = bx >> 4;
#pragma unroll
    for (int mf = 0; mf < 8; mf++) {
      const int s0 = (bx & 15) * 128 + mf * 16 + kg * 4;  // + i
#pragma unroll
      for (int cf = 0; cf < 4; cf++) {
        const int nt = ntb + cf;
        const float bv_ = bias[nt * 16 + lrow];
#pragma unroll
        for (int i = 0; i < 4; i++) {
          const int s = s0 + i;
          const size_t a = ((size_t)((b * 64 + (s >> 5)) * 64 + nt)) * 512 +
                           (s & 31) * 16 + lrow;
          O[a] = f2h_u(acc[mf][cf][i] + bv_);
        }
      }
    }
  } else {
    for (int kt = 0; kt < 32; kt++) {
      const size_t o = (size_t)kt * 512;
      f16x8 ah[8];
#pragma unroll
      for (int mf = 0; mf < 8; mf++)
        ah[mf] = *(const f16x8*)(xf + (size_t)mf * 32 * 512 + o);
#pragma unroll
      for (int cf = 0; cf < 4; cf++) {
        const size_t wo = ((size_t)(ntb + cf) * 32 + kt) * 512 + lane * 8;
        f16x8 bh = *(const f16x8*)(Wh + wo);
#pragma unroll
        for (int mf = 0; mf < 8; mf++) acc[mf][cf] = MFMA16F(ah[mf], bh, acc[mf][cf]);
      }
    }
    const int b = bx >> 4;
#pragma unroll
    for (int mf = 0; mf < 8; mf++) {
      const int kl_hi = (bx & 15) * 8 + mf;  // k_local >> 4
#pragma unroll
      for (int cf = 0; cf < 4; cf++) {
        const int d = (ntb + cf) * 16 + lrow;
        const float bv_ = bias[d];
        us4 pk;
#pragma unroll
        for (int i = 0; i < 4; i++) pk[i] = f2h_u(acc[mf][cf][i] + bv_);
        const size_t a = ((size_t)(b * 32 + (d >> 5)) * 128 + kl_hi) * 512 +
                         (size_t)(d & 31) * 16 + kg * 4;
        *reinterpret_cast<us4*>(&Vt[a]) = pk;
      }
    }
  }
}

// attn: one block per (batch, 32 q-rows); 16 waves / 1024 threads.
// Q staged in LDS (64 KB, later reused as P buffer). K/V register
// double-buffered prefetch. fp16 MFMA 32x32x16. (unchanged from R8)
__global__ __launch_bounds__(1024, 4) void attn_kernel(
    const unsigned short* __restrict__ Qf, const unsigned short* __restrict__ Kf,
    const unsigned short* __restrict__ Vt, float* __restrict__ out) {
  __shared__ unsigned short LDSB[65536];  // Q (first 32768) then P (all)
  __shared__ float redM[16][32];
  __shared__ float redS[16][32];
  __shared__ float rowinv[32];

  const int tid = threadIdx.x;
  const int lane = tid & 63;
  const int wid = tid >> 6;  // 0..15
  const int lq = lane & 31;
  const int hi = lane >> 5;
  const int lo16 = lq * 16 + hi * 8;

  const int id = blockIdx.x;
  const int xcd = id & 7;
  const int b = xcd >> 1;
  const int qt = (xcd & 1) + ((id >> 3) << 1);  // 0..63
  const int q0 = qt * 32;

  // ---- Stage Q tile (64 KB) into LDS ----
  {
    const unsigned short* qsrc = Qf + ((size_t)(b * 64 + qt) * 64) * 512;
#pragma unroll
    for (int i = 0; i < 4; i++) {
      const int idx = (i * 1024 + tid) * 8;
      *(us8*)&LDSB[idx] = *(const us8*)&qsrc[idx];
    }
  }
  __syncthreads();

  // ---- QK^T: fp16, K prefetched (reg double-buffer) ----
  f32x16 acc0, acc1, acc2, acc3;
#pragma unroll
  for (int r = 0; r < 16; r++) { acc0[r] = 0.f; acc1[r] = 0.f; acc2[r] = 0.f; acc3[r] = 0.f; }

  const unsigned short* kb = Kf + ((size_t)(b * 64 + wid * 4) * 64) * 512 + lo16;
#define KLD(G, KKK) (*(const f16x8*)(kb + (size_t)(G)*64 * 512 + (size_t)(KKK)*512))
  f16x8 kc0 = KLD(0, 0), kc1 = KLD(1, 0), kc2 = KLD(2, 0), kc3 = KLD(3, 0);
  for (int kk = 0; kk < 63; kk++) {
    f16x8 q = *(const f16x8*)&LDSB[kk * 512 + lo16];
    f16x8 kn0 = KLD(0, kk + 1), kn1 = KLD(1, kk + 1),
          kn2 = KLD(2, kk + 1), kn3 = KLD(3, kk + 1);
    __builtin_amdgcn_s_setprio(1);
    acc0 = MFMA32F(kc0, q, acc0);
    acc1 = MFMA32F(kc1, q, acc1);
    acc2 = MFMA32F(kc2, q, acc2);
    acc3 = MFMA32F(kc3, q, acc3);
    __builtin_amdgcn_s_setprio(0);
    kc0 = kn0; kc1 = kn1; kc2 = kn2; kc3 = kn3;
  }
  {
    f16x8 q = *(const f16x8*)&LDSB[63 * 512 + lo16];
    acc0 = MFMA32F(kc0, q, acc0);
    acc1 = MFMA32F(kc1, q, acc1);
    acc2 = MFMA32F(kc2, q, acc2);
    acc3 = MFMA32F(kc3, q, acc3);
  }
#undef KLD

  // ---- softmax (exact) ----
  float m = -3.0e38f;
#pragma unroll
  for (int r = 0; r < 16; r++) {
    m = fmaxf(m, fmaxf(fmaxf(acc0[r], acc1[r]), fmaxf(acc2[r], acc3[r])));
  }
  m = fmaxf(m, __shfl_xor(m, 32));
  if (hi == 0) redM[wid][lq] = m;
  __syncthreads();
  float M = redM[0][lq];
#pragma unroll
  for (int w = 1; w < 16; w++) M = fmaxf(M, redM[w][lq]);

  float s = 0.f;
#pragma unroll
  for (int r = 0; r < 16; r++) {
    acc0[r] = __expf(acc0[r] - M); s += acc0[r];
    acc1[r] = __expf(acc1[r] - M); s += acc1[r];
    acc2[r] = __expf(acc2[r] - M); s += acc2[r];
    acc3[r] = __expf(acc3[r] - M); s += acc3[r];
  }
  s += __shfl_xor(s, 32);
  if (hi == 0) redS[wid][lq] = s;
  __syncthreads();
  if (tid < 32) {
    float ss = 0.f;
#pragma unroll
    for (int w = 0; w < 16; w++) ss += redS[w][tid];
    rowinv[tid] = 1.0f / ss;
  }

  // ---- P -> fp16 LDS (XOR swizzle); overwrites Q region ----
  const int swz = (lq & 7) << 3;
  const int pb = lq * 2048 + wid * 128 + 4 * hi;
#define PWRITE(GG, ACC)                                                     \
  {                                                                         \
    _Pragma("unroll")                                                       \
    for (int qd = 0; qd < 4; qd++) {                                        \
      us4 pk;                                                               \
      _Pragma("unroll")                                                     \
      for (int i = 0; i < 4; i++) pk[i] = f2h_u(ACC[qd * 4 + i]);           \
      *(us4*)&LDSB[(pb + (GG)*32 + qd * 8) ^ swz] = pk;                     \
    }                                                                       \
  }
  PWRITE(0, acc0)
  PWRITE(1, acc1)
  PWRITE(2, acc2)
  PWRITE(3, acc3)
#undef PWRITE
  __syncthreads();

  // ---- O = P @ V, V prefetched ----
  f32x16 o0, o1;
#pragma unroll
  for (int r = 0; r < 16; r++) { o0[r] = 0.f; o1[r] = 0.f; }

  const unsigned short* vt0 = Vt + ((size_t)(b * 32 + wid * 2) * 128) * 512 + lo16;
  const unsigned short* vt1 = vt0 + (size_t)128 * 512;
  const int prow = lq * 2048 + hi * 8;
#define VLD(P, KKK) (*(const f16x8*)((P) + (size_t)(KKK)*512))
  f16x8 vc0 = VLD(vt0, 0), vc1 = VLD(vt1, 0);
  for (int kk = 0; kk < 127; kk++) {
    f16x8 pa = *(const f16x8*)&LDSB[(prow + kk * 16) ^ swz];
    f16x8 vn0 = VLD(vt0, kk + 1), vn1 = VLD(vt1, kk + 1);
    __builtin_amdgcn_s_setprio(1);
    o0 = MFMA32F(pa, vc0, o0);
    o1 = MFMA32F(pa, vc1, o1);
    __builtin_amdgcn_s_setprio(0);
    vc0 = vn0; vc1 = vn1;
  }
  {
    f16x8 pa = *(const f16x8*)&LDSB[(prow + 127 * 16) ^ swz];
    o0 = MFMA32F(pa, vc0, o0);
    o1 = MFMA32F(pa, vc1, o1);
  }
#undef VLD

  // ---- Epilogue ----
  float rv[16];
#pragma unroll
  for (int r = 0; r < 16; r++) rv[r] = rowinv[(r & 3) + 8 * (r >> 2) + 4 * hi];
  const int d0 = wid * 64 + lq;
#pragma unroll
  for (int r = 0; r < 16; r++) {
    const int q = (r & 3) + 8 * (r >> 2) + 4 * hi;
    const size_t ob = ((size_t)b * 2048 + q0 + q) * 1024;
    out[ob + d0] = o0[r] * rv[r];
    out[ob + d0 + 32] = o1[r] * rv[r];
  }
}

extern "C" void kernel_launch(void* const* d_in, const int* in_sizes, int n_in,
                              void* d_out, int out_size, void* d_ws, size_t ws_size,
                              hipStream_t stream) {
  const float* x  = (const float*)d_in[0];
  const float* Wq = (const float*)d_in[1];
  const float* bq = (const float*)d_in[2];
  const float* Wk = (const float*)d_in[3];
  const float* bk = (const float*)d_in[4];
  const float* Wv = (const float*)d_in[5];
  const float* bv = (const float*)d_in[6];
  float* o = (float*)d_out;

  const size_t NX = (size_t)8192 * 1024;
  const size_t NW = (size_t)1024 * 1024;
  unsigned short* p = (unsigned short*)d_ws;
  unsigned short* Xf = p; p += NX;
  unsigned short* Qf = p; p += NX;
  unsigned short* Kf = p; p += NX;
  unsigned short* Vt = p; p += NX;
  unsigned short* Wqh = p; p += NW;
  unsigned short* Wql = p; p += NW;
  unsigned short* Wkh = p; p += NW;
  unsigned short* Wkl = p; p += NW;
  unsigned short* Wvh = p; p += NW;
  unsigned short* Wvl = p; p += NW;

  split_x_kernel<<<4096, 256, 0, stream>>>(x, Xf, 16384);
  dim3 gs(512, 3);
  split3_kernel<<<gs, 256, 0, stream>>>(Wq, Wk, Wv, Wqh, Wql, Wkh, Wkl, Wvh, Wvl);

  dim3 gp(64, 4, 3), bp(256);
  proj_fused_kernel<<<gp, bp, 0, stream>>>(Xf, Wqh, Wql, Wkh, Wkl, Wvh,
                                           bq, bk, bv, Qf, Kf, Vt);

  attn_kernel<<<256, 1024, 0, stream>>>(Qf, Kf, Vt, o);
}

// Round 10
// 183.941 us; speedup vs baseline: 7.3005x; 1.0189x over previous
//
#include <hip/hip_runtime.h>
#include <hip/hip_bf16.h>

// B=4, S=2048, H=1024. Inputs/outputs fp32.
// Proj: 2-pass fp16 (X fp16 1-plane; W fp16 hi+lo planes), fp32 accum.
// Attn: split-K flash (2 key-halves), fp16 MFMA 32x32x16, fp32 softmax,
//       fp16 unnormalized partials + (m,l), combine kernel merges.
// Layouts (all fragment-native):
//   Xf / W planes: [rows/16][k/32][512] fp16; lane l's 8 elems at +l*8
//   Qf,Kf fp16: [b][s/32][h/16][srow 32][h 16]
//   Vt   fp16: [b][d/32][k/16][(d&31)*16 + (k&15)]
//   Opart fp16: [b*2+kh][s 2048][d 1024];  Mpart/Lpart fp32 [b*2+kh][2048]

typedef __attribute__((ext_vector_type(4))) float f32x4;
typedef __attribute__((ext_vector_type(16))) float f32x16;
typedef __attribute__((ext_vector_type(8))) _Float16 f16x8;
typedef __attribute__((ext_vector_type(4))) unsigned short us4;
typedef __attribute__((ext_vector_type(8))) unsigned short us8;

#define MFMA16F(a, b, c) __builtin_amdgcn_mfma_f32_16x16x32_f16((a), (b), (c), 0, 0, 0)
#define MFMA32F(a, b, c) __builtin_amdgcn_mfma_f32_32x32x16_f16((a), (b), (c), 0, 0, 0)

static __device__ __forceinline__ unsigned short f2h_u(float x) {
  _Float16 h = (_Float16)x;
  return *reinterpret_cast<unsigned short*>(&h);
}
static __device__ __forceinline__ float hu2f(unsigned short u) {
  _Float16 h;
  *reinterpret_cast<unsigned short*>(&h) = u;
  return (float)h;
}

// fp32 [rows][1024] -> fp16 fragment tiles [rows/16][32][512] (single plane).
__global__ __launch_bounds__(256) void split_x_kernel(
    const float* __restrict__ in, unsigned short* __restrict__ outp, int ntiles) {
  const int t = blockIdx.x * 256 + threadIdx.x;
  if (t >= ntiles * 64) return;
  const int tile = t >> 6;
  const int l = t & 63;
  const int m = (tile >> 5) * 16 + (l & 15);
  const int kb = (tile & 31) * 32 + (l >> 4) * 8;
  const float* src = in + (size_t)m * 1024 + kb;
  f32x4 v0 = *(const f32x4*)src;
  f32x4 v1 = *(const f32x4*)(src + 4);
  us8 h;
#pragma unroll
  for (int j = 0; j < 4; j++) {
    h[j] = f2h_u(v0[j]);
    h[j + 4] = f2h_u(v1[j]);
  }
  *(us8*)(outp + (size_t)tile * 512 + l * 8) = h;
}

// All three W splits (fp16 hi/lo); which==2 (V) skips lo store.
__global__ __launch_bounds__(256) void split3_kernel(
    const float* __restrict__ w0, const float* __restrict__ w1,
    const float* __restrict__ w2,
    unsigned short* __restrict__ h0, unsigned short* __restrict__ l0,
    unsigned short* __restrict__ h1, unsigned short* __restrict__ l1,
    unsigned short* __restrict__ h2, unsigned short* __restrict__ l2) {
  const int which = blockIdx.y;
  const float* in = which == 0 ? w0 : (which == 1 ? w1 : w2);
  unsigned short* hi = which == 0 ? h0 : (which == 1 ? h1 : h2);
  unsigned short* lo = which == 0 ? l0 : (which == 1 ? l1 : l2);
  const int t = blockIdx.x * 256 + threadIdx.x;
  const int tile = t >> 6;
  const int l = t & 63;
  const int m = (tile >> 5) * 16 + (l & 15);
  const int kb = (tile & 31) * 32 + (l >> 4) * 8;
  const float* src = in + (size_t)m * 1024 + kb;
  f32x4 v0 = *(const f32x4*)src;
  f32x4 v1 = *(const f32x4*)(src + 4);
  us8 h, lv;
#pragma unroll
  for (int j = 0; j < 4; j++) {
    unsigned short hu = f2h_u(v0[j]);
    h[j] = hu;
    lv[j] = f2h_u(v0[j] - hu2f(hu));
    hu = f2h_u(v1[j]);
    h[j + 4] = hu;
    lv[j + 4] = f2h_u(v1[j] - hu2f(hu));
  }
  *(us8*)(hi + (size_t)tile * 512 + l * 8) = h;
  if (which != 2) *(us8*)(lo + (size_t)tile * 512 + l * 8) = lv;
}

// Fused Q/K/V projection. Block: 128 m x 256 n, 4 waves (8mf x 4cf reg tile).
// grid (64, 4, 3). z=0: Q. z=1: K. z=2: V (1-pass, Vt store). (unchanged R9)
__global__ __launch_bounds__(256, 2) void proj_fused_kernel(
    const unsigned short* __restrict__ Xf,
    const unsigned short* __restrict__ Wqh, const unsigned short* __restrict__ Wql,
    const unsigned short* __restrict__ Wkh, const unsigned short* __restrict__ Wkl,
    const unsigned short* __restrict__ Wvh,
    const float* __restrict__ bq, const float* __restrict__ bk,
    const float* __restrict__ bv,
    unsigned short* __restrict__ Qf, unsigned short* __restrict__ Kf,
    unsigned short* __restrict__ Vt) {
  const int tid = threadIdx.x;
  const int lane = tid & 63;
  const int wid = tid >> 6;   // 0..3
  const int lrow = lane & 15;
  const int kg = lane >> 4;
  const int bx = blockIdx.x;               // 128-row m-block, 0..63
  const int ntb = blockIdx.y * 16 + wid * 4;
  const int z = blockIdx.z;

  const unsigned short* Wh = z == 0 ? Wqh : (z == 1 ? Wkh : Wvh);
  const unsigned short* Wl = z == 0 ? Wql : Wkl;
  const float* bias = z == 0 ? bq : (z == 1 ? bk : bv);

  const unsigned short* xf = Xf + (size_t)(bx * 8) * 32 * 512 + lane * 8;

  f32x4 acc[8][4];
#pragma unroll
  for (int mf = 0; mf < 8; mf++)
#pragma unroll
    for (int cf = 0; cf < 4; cf++) acc[mf][cf] = f32x4{0.f, 0.f, 0.f, 0.f};

  if (z < 2) {
    for (int kt = 0; kt < 32; kt++) {
      const size_t o = (size_t)kt * 512;
      f16x8 ah[8];
#pragma unroll
      for (int mf = 0; mf < 8; mf++)
        ah[mf] = *(const f16x8*)(xf + (size_t)mf * 32 * 512 + o);
#pragma unroll
      for (int cf = 0; cf < 4; cf++) {
        const size_t wo = ((size_t)(ntb + cf) * 32 + kt) * 512 + lane * 8;
        f16x8 bh = *(const f16x8*)(Wh + wo);
        f16x8 bl = *(const f16x8*)(Wl + wo);
#pragma unroll
        for (int mf = 0; mf < 8; mf++) {
          acc[mf][cf] = MFMA16F(ah[mf], bh, acc[mf][cf]);
          acc[mf][cf] = MFMA16F(ah[mf], bl, acc[mf][cf]);
        }
      }
    }
    unsigned short* O = z == 0 ? Qf : Kf;
    const int b = bx >> 4;
#pragma unroll
    for (int mf = 0; mf < 8; mf++) {
      const int s0 = (bx & 15) * 128 + mf * 16 + kg * 4;
#pragma unroll
      for (int cf = 0; cf < 4; cf++) {
        const int nt = ntb + cf;
        const float bv_ = bias[nt * 16 + lrow];
#pragma unroll
        for (int i = 0; i < 4; i++) {
          const int s = s0 + i;
          const size_t a = ((size_t)((b * 64 + (s >> 5)) * 64 + nt)) * 512 +
                           (s & 31) * 16 + lrow;
          O[a] = f2h_u(acc[mf][cf][i] + bv_);
        }
      }
    }
  } else {
    for (int kt = 0; kt < 32; kt++) {
      const size_t o = (size_t)kt * 512;
      f16x8 ah[8];
#pragma unroll
      for (int mf = 0; mf < 8; mf++)
        ah[mf] = *(const f16x8*)(xf + (size_t)mf * 32 * 512 + o);
#pragma unroll
      for (int cf = 0; cf < 4; cf++) {
        const size_t wo = ((size_t)(ntb + cf) * 32 + kt) * 512 + lane * 8;
        f16x8 bh = *(const f16x8*)(Wh + wo);
#pragma unroll
        for (int mf = 0; mf < 8; mf++) acc[mf][cf] = MFMA16F(ah[mf], bh, acc[mf][cf]);
      }
    }
    const int b = bx >> 4;
#pragma unroll
    for (int mf = 0; mf < 8; mf++) {
      const int kl_hi = (bx & 15) * 8 + mf;
#pragma unroll
      for (int cf = 0; cf < 4; cf++) {
        const int d = (ntb + cf) * 16 + lrow;
        const float bv_ = bias[d];
        us4 pk;
#pragma unroll
        for (int i = 0; i < 4; i++) pk[i] = f2h_u(acc[mf][cf][i] + bv_);
        const size_t a = ((size_t)(b * 32 + (d >> 5)) * 128 + kl_hi) * 512 +
                         (size_t)(d & 31) * 16 + kg * 4;
        *reinterpret_cast<us4*>(&Vt[a]) = pk;
      }
    }
  }
}

// attn partial: block = (batch b, key-half kh, 64-q tile qt). 16 waves.
// id&7 -> XCD: (b,kh) pinned per XCD => K/V streams (2.1 MB) L2-resident.
// Wave w: keys [w*64,+64) in QK; d-cols [w*64,+64) in PV.
__global__ __launch_bounds__(1024, 1) void attn_part_kernel(
    const unsigned short* __restrict__ Qf, const unsigned short* __restrict__ Kf,
    const unsigned short* __restrict__ Vt, unsigned short* __restrict__ Opart,
    float* __restrict__ Mpart, float* __restrict__ Lpart) {
  __shared__ unsigned short LDSB[65536];  // Q [kk64][qg2][512] -> P [64q][1024k]
  __shared__ float redM[16][64];
  __shared__ float redS[16][64];

  const int tid = threadIdx.x;
  const int lane = tid & 63;
  const int wid = tid >> 6;  // 0..15
  const int lq = lane & 31;
  const int hi = lane >> 5;
  const int lo16 = lq * 16 + hi * 8;

  const int id = blockIdx.x;
  const int xcd = id & 7;
  const int b = xcd >> 1;
  const int kh = xcd & 1;
  const int qt = id >> 3;  // 0..31

  // ---- stage Q (64 q x 1024 h = 128 KB) ----
  {
    const us8* qsrc = (const us8*)(Qf + ((size_t)(b * 64 + qt * 2) * 64) * 512);
    us8* qdst = (us8*)LDSB;
#pragma unroll
    for (int i = 0; i < 8; i++) {
      const int u = i * 1024 + tid;
      const int kk = u >> 7, rem = u & 127;
      qdst[u] = qsrc[(rem >> 6) * 4096 + kk * 64 + (rem & 63)];
    }
  }
  __syncthreads();

  // ---- QK^T: S^T[64 keys x 64 q] per wave ----
  f32x16 s00, s01, s10, s11;  // [kg][qg]
#pragma unroll
  for (int r = 0; r < 16; r++) { s00[r] = 0.f; s01[r] = 0.f; s10[r] = 0.f; s11[r] = 0.f; }

  const unsigned short* kb =
      Kf + ((size_t)(b * 64 + kh * 32 + wid * 2) * 64) * 512 + lo16;
#define KLD(G, KKK) (*(const f16x8*)(kb + (size_t)(G)*64 * 512 + (size_t)(KKK)*512))
  f16x8 kc0 = KLD(0, 0), kc1 = KLD(1, 0);
  for (int kk = 0; kk < 63; kk++) {
    f16x8 qA = *(const f16x8*)&LDSB[kk * 1024 + lo16];
    f16x8 qB = *(const f16x8*)&LDSB[kk * 1024 + 512 + lo16];
    f16x8 kn0 = KLD(0, kk + 1), kn1 = KLD(1, kk + 1);
    __builtin_amdgcn_s_setprio(1);
    s00 = MFMA32F(kc0, qA, s00);
    s01 = MFMA32F(kc0, qB, s01);
    s10 = MFMA32F(kc1, qA, s10);
    s11 = MFMA32F(kc1, qB, s11);
    __builtin_amdgcn_s_setprio(0);
    kc0 = kn0; kc1 = kn1;
  }
  {
    f16x8 qA = *(const f16x8*)&LDSB[63 * 1024 + lo16];
    f16x8 qB = *(const f16x8*)&LDSB[63 * 1024 + 512 + lo16];
    s00 = MFMA32F(kc0, qA, s00);
    s01 = MFMA32F(kc0, qB, s01);
    s10 = MFMA32F(kc1, qA, s10);
    s11 = MFMA32F(kc1, qB, s11);
  }
#undef KLD

  // ---- partial softmax (per-block max/sum; exact within key-half) ----
  float mA = -3.0e38f, mB = -3.0e38f;
#pragma unroll
  for (int r = 0; r < 16; r++) {
    mA = fmaxf(mA, fmaxf(s00[r], s10[r]));
    mB = fmaxf(mB, fmaxf(s01[r], s11[r]));
  }
  mA = fmaxf(mA, __shfl_xor(mA, 32));
  mB = fmaxf(mB, __shfl_xor(mB, 32));
  if (hi == 0) { redM[wid][lq] = mA; redM[wid][32 + lq] = mB; }
  __syncthreads();
  float MA = redM[0][lq], MB = redM[0][32 + lq];
#pragma unroll
  for (int w = 1; w < 16; w++) {
    MA = fmaxf(MA, redM[w][lq]);
    MB = fmaxf(MB, redM[w][32 + lq]);
  }
  float sA = 0.f, sB = 0.f;
#pragma unroll
  for (int r = 0; r < 16; r++) {
    s00[r] = __expf(s00[r] - MA); sA += s00[r];
    s10[r] = __expf(s10[r] - MA); sA += s10[r];
    s01[r] = __expf(s01[r] - MB); sB += s01[r];
    s11[r] = __expf(s11[r] - MB); sB += s11[r];
  }
  sA += __shfl_xor(sA, 32);
  sB += __shfl_xor(sB, 32);
  if (hi == 0) { redS[wid][lq] = sA; redS[wid][32 + lq] = sB; }

  // ---- P -> fp16 LDS [64 q][1024 k], XOR-swizzled (overwrites Q) ----
  const int swz = (lq & 7) << 3;
#define PW(ACC, QQ, KB)                                                       \
  {                                                                           \
    _Pragma("unroll")                                                         \
    for (int qd = 0; qd < 4; qd++) {                                          \
      us4 pk;                                                                 \
      _Pragma("unroll")                                                       \
      for (int i = 0; i < 4; i++) pk[i] = f2h_u(ACC[qd * 4 + i]);             \
      *(us4*)&LDSB[(((QQ)*1024) + (KB) + qd * 8 + 4 * hi) ^ swz] = pk;        \
    }                                                                         \
  }
  PW(s00, lq, wid * 64)
  PW(s01, 32 + lq, wid * 64)
  PW(s10, lq, wid * 64 + 32)
  PW(s11, 32 + lq, wid * 64 + 32)
#undef PW
  __syncthreads();

  // ---- per-row stats store ----
  if (tid < 64) {
    float M = redM[0][tid], L = redS[0][tid];
#pragma unroll
    for (int w = 1; w < 16; w++) {
      M = fmaxf(M, redM[w][tid]);
      L += redS[w][tid];
    }
    const size_t gi = (size_t)(b * 2 + kh) * 2048 + qt * 64 + tid;
    Mpart[gi] = M;
    Lpart[gi] = L;
  }

  // ---- PV: O_part[64 q x 64 d] per wave ----
  f32x16 o00, o01, o10, o11;  // [qg][dg]
#pragma unroll
  for (int r = 0; r < 16; r++) { o00[r] = 0.f; o01[r] = 0.f; o10[r] = 0.f; o11[r] = 0.f; }

  const unsigned short* vb =
      Vt + ((size_t)((b * 32 + wid * 2) * 128) + kh * 64) * 512 + lo16;
#define VLD(G, KKK) (*(const f16x8*)(vb + (size_t)(G)*128 * 512 + (size_t)(KKK)*512))
  f16x8 vc0 = VLD(0, 0), vc1 = VLD(1, 0);
  const int prA = lq * 1024 + hi * 8;
  const int prB = (32 + lq) * 1024 + hi * 8;
  for (int kk = 0; kk < 63; kk++) {
    f16x8 paA = *(const f16x8*)&LDSB[(prA + kk * 16) ^ swz];
    f16x8 paB = *(const f16x8*)&LDSB[(prB + kk * 16) ^ swz];
    f16x8 vn0 = VLD(0, kk + 1), vn1 = VLD(1, kk + 1);
    __builtin_amdgcn_s_setprio(1);
    o00 = MFMA32F(paA, vc0, o00);
    o01 = MFMA32F(paA, vc1, o01);
    o10 = MFMA32F(paB, vc0, o10);
    o11 = MFMA32F(paB, vc1, o11);
    __builtin_amdgcn_s_setprio(0);
    vc0 = vn0; vc1 = vn1;
  }
  {
    f16x8 paA = *(const f16x8*)&LDSB[(prA + 63 * 16) ^ swz];
    f16x8 paB = *(const f16x8*)&LDSB[(prB + 63 * 16) ^ swz];
    o00 = MFMA32F(paA, vc0, o00);
    o01 = MFMA32F(paA, vc1, o01);
    o10 = MFMA32F(paB, vc0, o10);
    o11 = MFMA32F(paB, vc1, o11);
  }
#undef VLD

  // ---- store fp16 unnormalized partials ----
  unsigned short* ob = Opart + ((size_t)(b * 2 + kh) * 2048 + qt * 64) * 1024;
  const int d0 = wid * 64 + lq;
#pragma unroll
  for (int r = 0; r < 16; r++) {
    const int crow = (r & 3) + 8 * (r >> 2) + 4 * hi;
    ob[(size_t)crow * 1024 + d0] = f2h_u(o00[r]);
    ob[(size_t)crow * 1024 + d0 + 32] = f2h_u(o01[r]);
    ob[(size_t)(crow + 32) * 1024 + d0] = f2h_u(o10[r]);
    ob[(size_t)(crow + 32) * 1024 + d0 + 32] = f2h_u(o11[r]);
  }
}

// combine: out = (w0*O0 + w1*O1) / (w0*l0 + w1*l1), w = exp(m - max(m0,m1)).
__global__ __launch_bounds__(256) void attn_combine_kernel(
    const unsigned short* __restrict__ Opart, const float* __restrict__ Mpart,
    const float* __restrict__ Lpart, float* __restrict__ out) {
  const int t = blockIdx.x * 256 + threadIdx.x;  // 1,048,576 threads
  const int row = t >> 7;        // b*2048 + sl
  const int dd = (t & 127) * 8;
  const int b = row >> 11, sl = row & 2047;
  const int i0 = (b * 2) * 2048 + sl, i1 = i0 + 2048;
  const float m0 = Mpart[i0], m1 = Mpart[i1];
  const float M = fmaxf(m0, m1);
  float w0 = __expf(m0 - M), w1 = __expf(m1 - M);
  const float inv = 1.0f / (w0 * Lpart[i0] + w1 * Lpart[i1]);
  w0 *= inv; w1 *= inv;
  const us8 o0 = *(const us8*)&Opart[(size_t)i0 * 1024 + dd];
  const us8 o1 = *(const us8*)&Opart[(size_t)i1 * 1024 + dd];
  float* op = out + (size_t)row * 1024 + dd;
  f32x4 r0, r1;
#pragma unroll
  for (int j = 0; j < 4; j++) {
    r0[j] = w0 * hu2f(o0[j]) + w1 * hu2f(o1[j]);
    r1[j] = w0 * hu2f(o0[j + 4]) + w1 * hu2f(o1[j + 4]);
  }
  *(f32x4*)op = r0;
  *(f32x4*)(op + 4) = r1;
}

extern "C" void kernel_launch(void* const* d_in, const int* in_sizes, int n_in,
                              void* d_out, int out_size, void* d_ws, size_t ws_size,
                              hipStream_t stream) {
  const float* x  = (const float*)d_in[0];
  const float* Wq = (const float*)d_in[1];
  const float* bq = (const float*)d_in[2];
  const float* Wk = (const float*)d_in[3];
  const float* bk = (const float*)d_in[4];
  const float* Wv = (const float*)d_in[5];
  const float* bv = (const float*)d_in[6];
  float* o = (float*)d_out;

  const size_t NX = (size_t)8192 * 1024;
  const size_t NW = (size_t)1024 * 1024;
  unsigned short* p = (unsigned short*)d_ws;
  unsigned short* Xf = p; p += NX;
  unsigned short* Qf = p; p += NX;
  unsigned short* Kf = p; p += NX;
  unsigned short* Vt = p; p += NX;
  unsigned short* Wqh = p; p += NW;
  unsigned short* Wql = p; p += NW;
  unsigned short* Wkh = p; p += NW;
  unsigned short* Wkl = p; p += NW;
  unsigned short* Wvh = p; p += NW;
  unsigned short* Wvl = p; p += NW;
  unsigned short* Opart = p; p += 2 * NX;          // 33.5 MB fp16 partials
  float* Mpart = (float*)p; p += 32768;            // 16384 fp32
  float* Lpart = (float*)p; p += 32768;

  split_x_kernel<<<4096, 256, 0, stream>>>(x, Xf, 16384);
  dim3 gs(512, 3);
  split3_kernel<<<gs, 256, 0, stream>>>(Wq, Wk, Wv, Wqh, Wql, Wkh, Wkl, Wvh, Wvl);

  dim3 gp(64, 4, 3), bp(256);
  proj_fused_kernel<<<gp, bp, 0, stream>>>(Xf, Wqh, Wql, Wkh, Wkl, Wvh,
                                           bq, bk, bv, Qf, Kf, Vt);

  attn_part_kernel<<<256, 1024, 0, stream>>>(Qf, Kf, Vt, Opart, Mpart, Lpart);
  attn_combine_kernel<<<4096, 256, 0, stream>>>(Opart, Mpart, Lpart, o);
}